// Round 17
// baseline (515.072 us; speedup 1.0000x reference)
//
#include <hip/hip_runtime.h>
#include <math.h>

#define NS 56        // B*(T-1)
#define NPIX 65536   // 256*256

static constexpr double D_PI = 3.14159265358979323846;

typedef __attribute__((ext_vector_type(8))) short short8;
typedef __attribute__((ext_vector_type(4))) float f32x4;
typedef __attribute__((ext_vector_type(16))) float f32x16;

__device__ inline unsigned short f2bf(float f) {
  union { float f; unsigned int u; } v; v.f = f;
  unsigned int r = v.u + 0x7FFFu + ((v.u >> 16) & 1u);
  return (unsigned short)(r >> 16);
}
__device__ inline float bf2f(unsigned short b) {
  union { float f; unsigned int u; } v; v.u = ((unsigned int)b) << 16;
  return v.f;
}

// ---------------- workspace layout (float offsets) ----------------
// part doubles: [0,1024) ae, [1024,1472) dyn-interior, [1472,1528) dyn-boundary
#define SLC      (NS * NPIX)
#define OFF_PART 0
#define OFF_CNT  3584
#define OFF_S    4096
#define OFF_HM   36864
#define OFF_H    102400                   // bf16 (half used)
#define OFF_QB   (OFF_H + SLC)            // bf16 (half used)
#define OFF_DQ0  (OFF_QB + SLC)
#define OFF_DQ1  (OFF_DQ0 + SLC / 2)
#define OFF_A1   (OFF_DQ1 + SLC / 2)
#define OFF_XP   (OFF_A1 + SLC / 2)
#define OFF_Z1   (OFF_XP + 2097152)
#define OFF_Z2   (OFF_Z1 + 8388608)
#define OFF_BC   (OFF_Z2 + 8388608)
#define OFF_XA   (OFF_BC + 8388608)
#define OFF_WT   (OFF_XA + 2097152)
// weight regions in SHORT offsets from wtb
#define W_IN    0
#define W_HID   10240
#define W_B1    47104
#define W_B21   83968
#define W_B22   120832
#define W_O1    157696
#define W_O2    166912

#define QCLAMP 1.0e12f
#define HCLAMP 1.0e15f

// ---------------- preamble: init + wprep + qg init + pack x + boundary-dyn ----------
__global__ __launch_bounds__(256) void k_preamble(const float* __restrict__ x,
                                                  const float* __restrict__ w_in,
                                                  const float* __restrict__ w_hid,
                                                  const float* __restrict__ w_b1,
                                                  const float* __restrict__ w_b21,
                                                  const float* __restrict__ w_b22,
                                                  const float* __restrict__ w_out,
                                                  unsigned short* __restrict__ S,
                                                  float* __restrict__ HM,
                                                  unsigned short* __restrict__ wtb,
                                                  unsigned short* __restrict__ h,
                                                  unsigned short* __restrict__ qb,
                                                  unsigned short* __restrict__ xp,
                                                  unsigned int* __restrict__ cnt,
                                                  double* __restrict__ part,
                                                  float dx2, float gf, float gfc) {
  const int blk = blockIdx.x;
  const int tid = threadIdx.x;
  if (blk < 256) {
    int idx = blk * 256 + tid;
    if (idx == 0) *cnt = 0u;
    int i = idx >> 8, j = idx & 255;
    float sv = 0.f, hv = 1.f;
    if (i < 254 && j < 254) {
      double arg = D_PI * (double)((i + 1) * (j + 1)) / 255.0;
      sv = (float)((2.0 / sqrt(510.0)) * sin(arg));
      double la = 2.0 * (cos(D_PI * (double)(i + 1) / 255.0) - 1.0) / (double)dx2
                + 2.0 * (cos(D_PI * (double)(j + 1) / 255.0) - 1.0) / (double)dx2;
      hv = (float)((9.81 / 1e-4) * la - 9.81 * 1e-4 / (2.7 * 2.7));
    }
    S[idx] = f2bf(sv);
    HM[idx] = hv;
  } else if (blk < 256 + 1008) {
    int jb = blk - 256;
    int job = jb / 144;
    int e = (jb - job * 144) * 256 + tid;
    const float* src;
    int dstOff, chunks, icpShift, icw, ic0, icReal, ocw, ocReal;
    switch (job) {
      case 0: src = w_in;  dstOff = W_IN;  chunks = 5;  icpShift = 4; icw = 15;  ic0 = 0;  icReal = 15; ocw = 64; ocReal = 64; break;
      case 1: src = w_hid; dstOff = W_HID; chunks = 18; icpShift = 6; icw = 64;  ic0 = 0;  icReal = 64; ocw = 64; ocReal = 64; break;
      case 2: src = w_b1;  dstOff = W_B1;  chunks = 18; icpShift = 6; icw = 64;  ic0 = 0;  icReal = 64; ocw = 64; ocReal = 64; break;
      case 3: src = w_b21; dstOff = W_B21; chunks = 18; icpShift = 6; icw = 64;  ic0 = 0;  icReal = 64; ocw = 64; ocReal = 64; break;
      case 4: src = w_b22; dstOff = W_B22; chunks = 18; icpShift = 6; icw = 64;  ic0 = 0;  icReal = 64; ocw = 64; ocReal = 64; break;
      case 5: src = w_out; dstOff = W_O1;  chunks = 18; icpShift = 6; icw = 128; ic0 = 0;  icReal = 64; ocw = 16; ocReal = 15; break;
      default: src = w_out; dstOff = W_O2; chunks = 18; icpShift = 6; icw = 128; ic0 = 64; icReal = 64; ocw = 16; ocReal = 15; break;
    }
    int total = chunks * 4 * ocw * 8;
    if (e < total) {
      int j = e & 7;
      int oc = (e >> 3) % ocw;
      int ckg = e / (8 * ocw);
      int kg = ckg & 3, c = ckg >> 2;
      int Kidx = c * 32 + kg * 8 + j;
      int tap = Kidx >> icpShift;
      int ic = Kidx & ((1 << icpShift) - 1);
      float v = 0.f;
      if (tap < 9 && ic < icReal && oc < ocReal)
        v = src[((size_t)oc * icw + ic0 + ic) * 9 + tap];
      wtb[dstOff + e] = f2bf(v);
    }
  } else if (blk < 256 + 1008 + 14336) {
    int idx = (blk - 1264) * 256 + tid;
    int s = idx >> 16, p = idx & 65535;
    int y = p >> 8, xx = p & 255;
    int b = s / 14, t = s - b * 14;
    const float* hb = x + (size_t)(b * 15 + t) * NPIX;
    float hc = hb[p];
    float qv;
    if (y >= 2 && y <= 252 && xx >= 2 && xx <= 252) {
      qv = gf * ((hb[p + 256] + hb[p - 256] - 2.f * hc) / dx2
               + (hb[p + 1] + hb[p - 1] - 2.f * hc) / dx2) - gfc * hc;
    } else {
      qv = -gfc * hc;
    }
    h[idx] = f2bf(hc);
    qb[idx] = f2bf(qv);
  } else if (blk < 256 + 1008 + 14336 + 1024) {
    int e = (blk - 15600) * 256 + tid;
    int b = e >> 16, p = e & 65535;
    const float* xb = x + (size_t)b * 15 * NPIX + p;
    union { unsigned short u16[16]; uint4 u4[2]; } vv;
#pragma unroll
    for (int c = 0; c < 15; ++c) vv.u16[c] = f2bf(xb[(size_t)c * NPIX]);
    vv.u16[15] = 0;
    uint4* dst = (uint4*)&xp[(size_t)e * 16];
    dst[0] = vv.u4[0];
    dst[1] = vv.u4[1];
  } else {
    // boundary dyn term (h frame == bf16(hb) forever)
    int s = blk - 16624;
    int b = s / 14, t = s - b * 14;
    const float* hb = x + (size_t)(b * 15 + t) * NPIX;
    const float* x1 = x + (size_t)(b * 15 + t + 1) * NPIX;
    double sum = 0.0;
    for (int i = tid; i < 1020; i += 256) {
      int y, xc;
      if (i < 256)      { y = 0;         xc = i; }
      else if (i < 512) { y = 255;       xc = i - 256; }
      else if (i < 766) { y = i - 511;   xc = 0; }
      else              { y = i - 765;   xc = 255; }
      int p = y * 256 + xc;
      float d = x1[p] - bf2f(f2bf(hb[p]));
      sum += (double)d * (double)d;
    }
    for (int o = 32; o > 0; o >>= 1) sum += __shfl_down(sum, o);
    __shared__ double sw[4];
    int lane = tid & 63, wid = tid >> 6;
    if (lane == 0) sw[wid] = sum;
    __syncthreads();
    if (tid == 0) part[1472 + s] = sw[0] + sw[1] + sw[2] + sw[3];
  }
}

// ---------------- qrhs delta form (bf16 h/qb), UNCONDITIONAL wrapped dq loads -------
template <bool FIRST>
__global__ __launch_bounds__(256) void k_qrhs_dq(const unsigned short* __restrict__ h,
                                                 const unsigned short* __restrict__ qbb,
                                                 const unsigned short* __restrict__ dqin,
                                                 unsigned short* __restrict__ dqout,
                                                 float ngf, float pgf, float fdx,
                                                 float cc, float dtf) {
  int idx = blockIdx.x * 256 + threadIdx.x;
  int s = idx >> 16, p = idx & 65535;
  int y = p >> 8, xx = p & 255;
  const unsigned short* H = h + (size_t)s * NPIX;
  const unsigned short* QB = qbb + (size_t)s * NPIX;
  const unsigned short* DQ = dqin + (size_t)s * NPIX;
  const int base = p - 257;
  auto dqv = [&](int d) -> float {
    if (FIRST) return 0.f;
    return bf2f(DQ[(base + d) & 65535]);
  };
  float q1mqb = 0.f;
  if (y >= 2 && y <= 252 && xx >= 2 && xx <= 252) {
    float hSW = bf2f(H[p + 255]), hS = bf2f(H[p + 256]), hSE = bf2f(H[p + 257]);
    float hNW = bf2f(H[p - 257]), hN = bf2f(H[p - 256]), hNE = bf2f(H[p - 255]);
    float hW = bf2f(H[p - 1]), hE = bf2f(H[p + 1]);
    float uA = ngf * (hSW + hS - hN - hNW) / fdx;
    float uB = ngf * (hS + hSE - hNE - hN) / fdx;
    float vA = pgf * (hE + hNE - hNW - hW) / fdx;
    float vB = pgf * (hSE + hE - hW - hSW) / fdx;
    float uT = 0.5f * (uA + uB);
    float vT = 0.5f * (vA + vB);
    float up = fmaxf(uT, 0.f), um = fminf(uT, 0.f);
    float vp = fmaxf(vT, 0.f), vm = fminf(vT, 0.f);
    float qbc = bf2f(QB[p]);
    float Q0 = qbc + dqv(0);
    float QE = bf2f(QB[p + 1]) + dqv(1), QW = bf2f(QB[p - 1]) + dqv(-1);
    float QEE = bf2f(QB[p + 2]) + dqv(2), QWW = bf2f(QB[p - 2]) + dqv(-2);
    float QS = bf2f(QB[p + 256]) + dqv(256), QN = bf2f(QB[p - 256]) + dqv(-256);
    float QSS = bf2f(QB[p + 512]) + dqv(512), QNN = bf2f(QB[p - 512]) + dqv(-512);
    float r = -up * cc * (2.f * QE + 3.f * Q0 - 6.f * QW + QWW)
            + um * cc * (QEE - 6.f * QE + 3.f * Q0 + 2.f * QW)
            - vp * cc * (2.f * QS + 3.f * Q0 - 6.f * QN + QNN)
            + vm * cc * (QSS - 6.f * QS + 3.f * Q0 + 2.f * QN);
    float q1 = Q0 + dtf * r;
    q1 = fminf(fmaxf(q1, -QCLAMP), QCLAMP);
    q1mqb = q1 - qbc;
  }
  int wy = (y == 0) ? 254 : ((y == 255) ? 255 : y - 1);
  int wx = (xx == 0) ? 254 : ((xx == 255) ? 255 : xx - 1);
  dqout[(size_t)s * NPIX + wy * 256 + wx] = f2bf(q1mqb);
}

// ---------------- solve core: acc2 = S @ (S @ X^T)^T for one (s,q,w) ----------------
__device__ inline f32x16 solve_core(const unsigned short* __restrict__ Sm,
                                    const unsigned short* __restrict__ X,
                                    unsigned short* __restrict__ Ul,
                                    int q, int w, int r31, int kh) {
  f32x16 acc;
#pragma unroll
  for (int i = 0; i < 16; ++i) acc[i] = 0.f;
  {
    const int ar = (32 * q + r31) * 256;
    const int br = (32 * w + r31) * 256;
#pragma unroll 4
    for (int kc = 0; kc < 256; kc += 16) {
      short8 a = *(const short8*)&Sm[ar + kc + kh * 8];
      short8 b = *(const short8*)&X[br + kc + kh * 8];
      acc = __builtin_amdgcn_mfma_f32_32x32x16_bf16(a, b, acc, 0, 0, 0);
    }
  }
  {
    const int col = 32 * w + r31;
    const int g = col >> 3, c7 = col & 7;
#pragma unroll
    for (int reg = 0; reg < 16; ++reg) {
      int i = (reg & 3) + 8 * (reg >> 2) + 4 * kh;
      Ul[i * 256 + (((g ^ (i & 7)) << 3) | c7)] = f2bf(acc[reg]);
    }
  }
  __syncthreads();
  f32x16 acc2;
#pragma unroll
  for (int i = 0; i < 16; ++i) acc2[i] = 0.f;
  {
    const int ar = (32 * w + r31) * 256;
    const int urow = r31 * 256;
    const int x7 = (r31 & 7);
#pragma unroll 4
    for (int kc = 0; kc < 256; kc += 16) {
      int g0 = (kc >> 3) + kh;
      short8 a = *(const short8*)&Sm[ar + kc + kh * 8];
      short8 b = *(const short8*)&Ul[urow + ((g0 ^ x7) << 3)];
      acc2 = __builtin_amdgcn_mfma_f32_32x32x16_bf16(a, b, acc2, 0, 0, 0);
    }
  }
  return acc2;
}

// ---------------- fused half-solve: one dstI2D ----------------
template <int EPI>
__global__ __launch_bounds__(512) void k_solve(const unsigned short* __restrict__ Sm,
                                               const unsigned short* __restrict__ Xb,
                                               unsigned short* __restrict__ Ob,
                                               const float* __restrict__ HM,
                                               const float* __restrict__ xin,
                                               unsigned short* __restrict__ hout,
                                               double* __restrict__ part) {
  __shared__ unsigned short Ul[32 * 256];
  const int s = blockIdx.x, q = blockIdx.y;
  const int lane = threadIdx.x & 63, w = threadIdx.x >> 6;
  const int r31 = lane & 31, kh = lane >> 5;
  f32x16 acc2 = solve_core(Sm, Xb + (size_t)s * NPIX, Ul, q, w, r31, kh);
  const int gn = 32 * q + r31;
  if (EPI == 0) {
    unsigned short* O = Ob + (size_t)s * NPIX;
#pragma unroll
    for (int reg = 0; reg < 16; ++reg) {
      int gm = 32 * w + (reg & 3) + 8 * (reg >> 2) + 4 * kh;
      O[(size_t)gm * 256 + gn] = f2bf(acc2[reg] / HM[(size_t)gm * 256 + gn]);
    }
  } else if (EPI == 1) {
    int b = s / 14, t = s - b * 14;
    const float* hb = xin + (size_t)(b * 15 + t) * NPIX;
    unsigned short* H = hout + (size_t)s * NPIX;
    if (gn < 254) {
#pragma unroll
      for (int reg = 0; reg < 16; ++reg) {
        int gm = 32 * w + (reg & 3) + 8 * (reg >> 2) + 4 * kh;
        if (gm < 254) {
          size_t o = (size_t)(gm + 1) * 256 + (gn + 1);
          float hv = acc2[reg] + hb[o];
          H[o] = f2bf(fminf(fmaxf(hv, -HCLAMP), HCLAMP));
        }
      }
    }
  } else {
    int b = s / 14, t = s - b * 14;
    const float* hb = xin + (size_t)(b * 15 + t) * NPIX;
    const float* x1 = xin + (size_t)(b * 15 + t + 1) * NPIX;
    double dsum = 0.0;
    if (gn < 254) {
#pragma unroll
      for (int reg = 0; reg < 16; ++reg) {
        int gm = 32 * w + (reg & 3) + 8 * (reg >> 2) + 4 * kh;
        if (gm < 254) {
          size_t o = (size_t)(gm + 1) * 256 + (gn + 1);
          float hv = acc2[reg] + hb[o];
          hv = fminf(fmaxf(hv, -HCLAMP), HCLAMP);
          float d = x1[o] - hv;
          dsum += (double)d * (double)d;
        }
      }
    }
    for (int o = 32; o > 0; o >>= 1) dsum += __shfl_down(dsum, o);
    __shared__ double sred[8];
    if (lane == 0) sred[w] = dsum;
    __syncthreads();
    if (threadIdx.x == 0) {
      double t8 = 0.0;
#pragma unroll
      for (int i = 0; i < 8; ++i) t8 += sred[i];
      part[1024 + s * 8 + q] = t8;
    }
  }
}

// ---------------- conv64 via MFMA 32x32x16: wave = 32-px group x 64 oc -------------
// Per k-chunk (tap,u): 1 ds_read (A) + 2 weight loads + 2 MFMA_32 -> MFMA-bound.
template <bool RELU>
__global__ __launch_bounds__(512) void k_conv64b(const unsigned short* __restrict__ in,
                                                 const unsigned short* __restrict__ wt,
                                                 const float* __restrict__ bias,
                                                 unsigned short* __restrict__ out) {
  __shared__ unsigned short tile[324 * 64];
  const int tid = threadIdx.x;
  const int lane = tid & 63, wv = tid >> 6;
  const int p31 = lane & 31, kh = lane >> 5;
  const int b = blockIdx.z;
  const int gx0 = blockIdx.x * 16, gy0 = blockIdx.y * 16;

  f32x16 acc[2];
#pragma unroll
  for (int j = 0; j < 2; ++j) {
    float bv = bias[j * 32 + p31];
#pragma unroll
    for (int i = 0; i < 16; ++i) acc[j][i] = bv;
  }

  const unsigned short* inb = in + (size_t)b * NPIX * 64;
  for (int c = tid; c < 2592; c += 512) {
    int pp = c >> 3, g = c & 7;
    int ly = pp / 18, lx = pp - ly * 18;
    int iy = gy0 + ly - 1, ix = gx0 + lx - 1;
    uint4 v = make_uint4(0u, 0u, 0u, 0u);
    if (iy >= 0 && iy < 256 && ix >= 0 && ix < 256)
      v = *(const uint4*)&inb[((size_t)iy * 256 + ix) * 64 + g * 8];
    int sw = g ^ (pp & 7);
    *(uint4*)&tile[pp * 64 + sw * 8] = v;
  }
  __syncthreads();

  const int pr = p31 >> 4, pc = p31 & 15;
#pragma unroll 4
  for (int cm = 0; cm < 36; ++cm) {
    const int tap = cm >> 2, u = cm & 3;
    const int dy = tap / 3, dxx = tap - dy * 3;
    const int cw = 2 * tap + (u >> 1);
    const int kgb = (u & 1) * 2 + kh;
    short8 bfr[2];
#pragma unroll
    for (int j = 0; j < 2; ++j)
      bfr[j] = *(const short8*)&wt[(((size_t)cw * 4 + kgb) * 64 + j * 32 + p31) * 8];
    const int pp = (2 * wv + pr + dy) * 18 + pc + dxx;
    const int g2 = (2 * u + kh) ^ (pp & 7);
    short8 av = *(const short8*)&tile[pp * 64 + g2 * 8];
#pragma unroll
    for (int j = 0; j < 2; ++j)
      acc[j] = __builtin_amdgcn_mfma_f32_32x32x16_bf16(av, bfr[j], acc[j], 0, 0, 0);
  }

  const size_t outBase = (size_t)b * NPIX * 64;
#pragma unroll
  for (int reg = 0; reg < 16; ++reg) {
    int px = (reg & 3) + 8 * (reg >> 2) + 4 * kh;
    int y = gy0 + 2 * wv + (px >> 4);
    int xc = gx0 + (px & 15);
    size_t ob = outBase + ((size_t)y * 256 + xc) * 64;
#pragma unroll
    for (int j = 0; j < 2; ++j) {
      float v = acc[j][reg];
      if (RELU) v = fmaxf(v, 0.f);
      out[ob + j * 32 + p31] = f2bf(v);
    }
  }
}

// ---------------- k_conv3 via MFMA 32x32x16: b1 -> z1, then b21*b22 -> bc ----------
__global__ __launch_bounds__(512) void k_conv3(const unsigned short* __restrict__ in,
                                               const unsigned short* __restrict__ wt1,
                                               const unsigned short* __restrict__ wtA,
                                               const unsigned short* __restrict__ wtB,
                                               const float* __restrict__ bias1,
                                               const float* __restrict__ biasA,
                                               const float* __restrict__ biasB,
                                               unsigned short* __restrict__ out1,
                                               unsigned short* __restrict__ outm) {
  __shared__ unsigned short tile[324 * 64];
  const int tid = threadIdx.x;
  const int lane = tid & 63, wv = tid >> 6;
  const int p31 = lane & 31, kh = lane >> 5;
  const int b = blockIdx.z;
  const int gx0 = blockIdx.x * 16, gy0 = blockIdx.y * 16;
  const size_t outBase = (size_t)b * NPIX * 64;
  const int pr = p31 >> 4, pc = p31 & 15;

  const unsigned short* inb = in + (size_t)b * NPIX * 64;
  for (int c = tid; c < 2592; c += 512) {
    int pp = c >> 3, g = c & 7;
    int ly = pp / 18, lx = pp - ly * 18;
    int iy = gy0 + ly - 1, ix = gx0 + lx - 1;
    uint4 v = make_uint4(0u, 0u, 0u, 0u);
    if (iy >= 0 && iy < 256 && ix >= 0 && ix < 256)
      v = *(const uint4*)&inb[((size_t)iy * 256 + ix) * 64 + g * 8];
    int sw = g ^ (pp & 7);
    *(uint4*)&tile[pp * 64 + sw * 8] = v;
  }
  __syncthreads();

  // ---- phase 1: b1 conv ----
  {
    f32x16 acc[2];
#pragma unroll
    for (int j = 0; j < 2; ++j) {
      float bv = bias1[j * 32 + p31];
#pragma unroll
      for (int i = 0; i < 16; ++i) acc[j][i] = bv;
    }
#pragma unroll 4
    for (int cm = 0; cm < 36; ++cm) {
      const int tap = cm >> 2, u = cm & 3;
      const int dy = tap / 3, dxx = tap - dy * 3;
      const int cw = 2 * tap + (u >> 1);
      const int kgb = (u & 1) * 2 + kh;
      short8 bfr[2];
#pragma unroll
      for (int j = 0; j < 2; ++j)
        bfr[j] = *(const short8*)&wt1[(((size_t)cw * 4 + kgb) * 64 + j * 32 + p31) * 8];
      const int pp = (2 * wv + pr + dy) * 18 + pc + dxx;
      const int g2 = (2 * u + kh) ^ (pp & 7);
      short8 av = *(const short8*)&tile[pp * 64 + g2 * 8];
#pragma unroll
      for (int j = 0; j < 2; ++j)
        acc[j] = __builtin_amdgcn_mfma_f32_32x32x16_bf16(av, bfr[j], acc[j], 0, 0, 0);
    }
#pragma unroll
    for (int reg = 0; reg < 16; ++reg) {
      int px = (reg & 3) + 8 * (reg >> 2) + 4 * kh;
      int y = gy0 + 2 * wv + (px >> 4);
      int xc = gx0 + (px & 15);
      size_t ob = outBase + ((size_t)y * 256 + xc) * 64;
#pragma unroll
      for (int j = 0; j < 2; ++j)
        out1[ob + j * 32 + p31] = f2bf(acc[j][reg]);
    }
  }

  // ---- phase 2: b21 and b22, write product ----
  {
    f32x16 accA[2], accB[2];
#pragma unroll
    for (int j = 0; j < 2; ++j) {
      float ba = biasA[j * 32 + p31], bb = biasB[j * 32 + p31];
#pragma unroll
      for (int i = 0; i < 16; ++i) { accA[j][i] = ba; accB[j][i] = bb; }
    }
#pragma unroll 2
    for (int cm = 0; cm < 36; ++cm) {
      const int tap = cm >> 2, u = cm & 3;
      const int dy = tap / 3, dxx = tap - dy * 3;
      const int cw = 2 * tap + (u >> 1);
      const int kgb = (u & 1) * 2 + kh;
      short8 wa[2], wb[2];
#pragma unroll
      for (int j = 0; j < 2; ++j) {
        wa[j] = *(const short8*)&wtA[(((size_t)cw * 4 + kgb) * 64 + j * 32 + p31) * 8];
        wb[j] = *(const short8*)&wtB[(((size_t)cw * 4 + kgb) * 64 + j * 32 + p31) * 8];
      }
      const int pp = (2 * wv + pr + dy) * 18 + pc + dxx;
      const int g2 = (2 * u + kh) ^ (pp & 7);
      short8 av = *(const short8*)&tile[pp * 64 + g2 * 8];
#pragma unroll
      for (int j = 0; j < 2; ++j) {
        accA[j] = __builtin_amdgcn_mfma_f32_32x32x16_bf16(av, wa[j], accA[j], 0, 0, 0);
        accB[j] = __builtin_amdgcn_mfma_f32_32x32x16_bf16(av, wb[j], accB[j], 0, 0, 0);
      }
    }
#pragma unroll
    for (int reg = 0; reg < 16; ++reg) {
      int px = (reg & 3) + 8 * (reg >> 2) + 4 * kh;
      int y = gy0 + 2 * wv + (px >> 4);
      int xc = gx0 + (px & 15);
      size_t ob = outBase + ((size_t)y * 256 + xc) * 64;
#pragma unroll
      for (int j = 0; j < 2; ++j)
        outm[ob + j * 32 + p31] = f2bf(accA[j][reg] * accB[j][reg]);
    }
  }
}

// ---------------- out conv: dual source, 16 oc, 512 thr (2 rows/wave) -------------
__global__ __launch_bounds__(512) void k_convout(const unsigned short* __restrict__ in0,
                                                 const unsigned short* __restrict__ in1,
                                                 const unsigned short* __restrict__ wt,
                                                 const float* __restrict__ bias,
                                                 unsigned short* __restrict__ out) {
  __shared__ unsigned short tile[324 * 64];
  const int tid = threadIdx.x;
  const int lane = tid & 63, wave = tid >> 6;
  const int cl = lane & 15, kg = lane >> 4;
  const int b = blockIdx.z;
  const int gx0 = blockIdx.x * 16, gy0 = blockIdx.y * 16;

  f32x4 acc[2];
  {
    float bv = (cl < 15) ? bias[cl] : 0.f;
    acc[0] = (f32x4){bv, bv, bv, bv};
    acc[1] = acc[0];
  }

  for (int src = 0; src < 2; ++src) {
    const unsigned short* inb = (src ? in1 : in0) + (size_t)b * NPIX * 64;
    const unsigned short* wtp = wt + src * 9216;
    if (src) __syncthreads();
    for (int c = tid; c < 2592; c += 512) {
      int pp = c >> 3, g = c & 7;
      int ly = pp / 18, lx = pp - ly * 18;
      int iy = gy0 + ly - 1, ix = gx0 + lx - 1;
      uint4 v = make_uint4(0u, 0u, 0u, 0u);
      if (iy >= 0 && iy < 256 && ix >= 0 && ix < 256)
        v = *(const uint4*)&inb[((size_t)iy * 256 + ix) * 64 + g * 8];
      int sw = g ^ (pp & 7);
      *(uint4*)&tile[pp * 64 + sw * 8] = v;
    }
    __syncthreads();
#pragma unroll 3
    for (int cm = 0; cm < 18; ++cm) {
      const int tap = cm >> 1;
      const int g = (cm & 1) * 4 + kg;
      const int dy = tap / 3, dxx = tap - dy * 3;
      short8 bfr = *(const short8*)&wtp[(((size_t)cm * 4 + kg) * 16 + cl) * 8];
      const int tc = cl + dxx;
#pragma unroll
      for (int i = 0; i < 2; ++i) {
        int pp = (wave * 2 + i + dy) * 18 + tc;
        int g2 = g ^ (pp & 7);
        short8 av = *(const short8*)&tile[pp * 64 + g2 * 8];
        acc[i] = __builtin_amdgcn_mfma_f32_16x16x32_bf16(av, bfr, acc[i], 0, 0, 0);
      }
    }
  }

  const size_t outBase = (size_t)b * NPIX * 16;
#pragma unroll
  for (int i = 0; i < 2; ++i) {
    int y = gy0 + wave * 2 + i;
#pragma unroll
    for (int r = 0; r < 4; ++r) {
      int px = gx0 + kg * 4 + r;
      size_t oi = outBase + ((size_t)y * 256 + px) * 16 + cl;
      out[oi] = f2bf(acc[i][r]);
    }
  }
}

// ---------------- conv16 (conv_in), 256 thr ----------------
__global__ __launch_bounds__(256) void k_conv16(const unsigned short* __restrict__ in,
                                                const unsigned short* __restrict__ wt,
                                                const float* __restrict__ bias,
                                                unsigned short* __restrict__ out) {
  __shared__ unsigned short wlds[10240];
  __shared__ unsigned short tile[324 * 16];

  const int tid = threadIdx.x;
  const int lane = tid & 63, wave = tid >> 6;
  const int cl = lane & 15, kg = lane >> 4;
  const int b = blockIdx.z;
  const int gx0 = blockIdx.x * 16, gy0 = blockIdx.y * 16;

  {
    uint4* wl = (uint4*)wlds;
    const uint4* wg = (const uint4*)wt;
    for (int i = tid; i < 1280; i += 256) wl[i] = wg[i];
  }
  const unsigned short* inb = in + (size_t)b * NPIX * 16;
  for (int c = tid; c < 648; c += 256) {
    int pp = c >> 1, g = c & 1;
    int ly = pp / 18, lx = pp - ly * 18;
    int iy = gy0 + ly - 1, ix = gx0 + lx - 1;
    uint4 v = make_uint4(0u, 0u, 0u, 0u);
    if (iy >= 0 && iy < 256 && ix >= 0 && ix < 256)
      v = *(const uint4*)&inb[((size_t)iy * 256 + ix) * 16 + g * 8];
    int sw = g ^ (pp & 1);
    *(uint4*)&tile[pp * 16 + sw * 8] = v;
  }
  __syncthreads();

  f32x4 acc[4][4];
#pragma unroll
  for (int j = 0; j < 4; ++j) {
    float bv = bias[j * 16 + cl];
#pragma unroll
    for (int i = 0; i < 4; ++i) acc[i][j] = (f32x4){bv, bv, bv, bv};
  }

#pragma unroll
  for (int c = 0; c < 5; ++c) {
    int tap = 2 * c + (kg >> 1);
    int dy = tap / 3, dxx = tap - dy * 3;
    int gidx = kg & 1;
    short8 bfr[4];
#pragma unroll
    for (int j = 0; j < 4; ++j)
      bfr[j] = *(const short8*)&wlds[((c * 4 + kg) * 64 + j * 16 + cl) * 8];
    int tc = cl + dxx;
#pragma unroll
    for (int i = 0; i < 4; ++i) {
      int tr = wave * 4 + i + dy;
      if (tr > 17) tr = 17;
      int pp = tr * 18 + tc;
      int g2 = gidx ^ (pp & 1);
      short8 av = *(const short8*)&tile[pp * 16 + g2 * 8];
#pragma unroll
      for (int j = 0; j < 4; ++j)
        acc[i][j] = __builtin_amdgcn_mfma_f32_16x16x32_bf16(av, bfr[j], acc[i][j], 0, 0, 0);
    }
  }

  const size_t outBase = (size_t)b * NPIX * 64;
#pragma unroll
  for (int i = 0; i < 4; ++i) {
    int y = gy0 + wave * 4 + i;
#pragma unroll
    for (int j = 0; j < 4; ++j) {
      int oc = j * 16 + cl;
#pragma unroll
      for (int r = 0; r < 4; ++r) {
        int px = gx0 + kg * 4 + r;
        size_t oi = outBase + ((size_t)y * 256 + px) * 64 + oc;
        out[oi] = f2bf(fmaxf(acc[i][j][r], 0.f));
      }
    }
  }
}

// ---------------- ae reduction (coalesced) + ticket final ----------------
__global__ __launch_bounds__(256) void k_red_ae(const float* __restrict__ x,
                                                const unsigned short* __restrict__ xa,
                                                double* __restrict__ part,
                                                unsigned int* __restrict__ cnt,
                                                float* __restrict__ out) {
  const int NBT = 1024;
  const int bid = blockIdx.x;
  const int tid = threadIdx.x;
  const int e = bid * 256 + tid;
  const int b = e >> 16, p = e & 65535;
  union { unsigned short u16[16]; uint4 u4[2]; } vv;
  const uint4* xap = (const uint4*)&xa[(size_t)e * 16];
  vv.u4[0] = xap[0];
  vv.u4[1] = xap[1];
  const float* xb = x + (size_t)b * 15 * NPIX + p;
  double sum = 0.0;
#pragma unroll
  for (int c = 0; c < 15; ++c) {
    float d = xb[(size_t)c * NPIX] - bf2f(vv.u16[c]);
    sum += (double)d * (double)d;
  }
  for (int o = 32; o > 0; o >>= 1) sum += __shfl_down(sum, o);
  __shared__ double sw[4];
  __shared__ bool last;
  int lane = tid & 63, wid = tid >> 6;
  if (lane == 0) sw[wid] = sum;
  __syncthreads();
  if (tid == 0) {
    part[bid] = sw[0] + sw[1] + sw[2] + sw[3];
    __threadfence();
    unsigned int t = atomicAdd(cnt, 1u);
    last = (t == (unsigned)(NBT - 1));
  }
  __syncthreads();
  if (last) {
    __threadfence();
    double s1 = 0.0, s2 = 0.0;
    for (int i = tid; i < 504; i += 256) s1 += part[1024 + i];
    for (int i = tid; i < NBT; i += 256) s2 += part[i];
    for (int o = 32; o > 0; o >>= 1) {
      s1 += __shfl_down(s1, o);
      s2 += __shfl_down(s2, o);
    }
    __shared__ double a1[4], a2[4];
    if (lane == 0) { a1[wid] = s1; a2[wid] = s2; }
    __syncthreads();
    if (tid == 0) {
      double v = (a1[0] + a1[1] + a1[2] + a1[3]) / (double)(NS * NPIX)
               + (a2[0] + a2[1] + a2[2] + a2[3]) / (double)(60 * NPIX);
      if (!(v == v)) v = 0.0;
      if (v > 1.0e30) v = 1.0e30;
      if (v < -1.0e30) v = -1.0e30;
      out[0] = (float)v;
    }
  }
}

// ---------------- launcher ----------------
extern "C" void kernel_launch(void* const* d_in, const int* in_sizes, int n_in,
                              void* d_out, int out_size, void* d_ws, size_t ws_size,
                              hipStream_t stream) {
  (void)in_sizes; (void)n_in; (void)out_size; (void)ws_size;
  const float* x     = (const float*)d_in[0];
  const float* w_in  = (const float*)d_in[1];
  const float* b_in  = (const float*)d_in[2];
  const float* w_hid = (const float*)d_in[3];
  const float* b_hid = (const float*)d_in[4];
  const float* w_b1  = (const float*)d_in[5];
  const float* b_b1  = (const float*)d_in[6];
  const float* w_b21 = (const float*)d_in[7];
  const float* b_b21 = (const float*)d_in[8];
  const float* w_b22 = (const float*)d_in[9];
  const float* b_b22 = (const float*)d_in[10];
  const float* w_out = (const float*)d_in[11];
  const float* b_out = (const float*)d_in[12];
  float* ws = (float*)d_ws;
  float* out = (float*)d_out;

  double mc = 0.0;
  for (int k = 0; k < 256; ++k) mc += cos((32.0 + 0.05 * k) * D_PI / 180.0);
  mc /= 256.0;
  float DXf = (float)(0.5 * (5550.0 + 5550.0 * mc));
  float dx2 = DXf * DXf;
  float gf  = (float)(9.81 / 1e-4);
  float ngf = (float)(-9.81 / 1e-4);
  float gfc = (float)(9.81 * 1e-4 / (2.7 * 2.7));
  float fdx = 4.0f * DXf;
  float cc  = 1.0f / (6.0f * DXf);
  float dtf = 21600.0f;

  double* part = (double*)d_ws;
  unsigned int* cnt = (unsigned int*)(ws + OFF_CNT);
  unsigned short* S  = (unsigned short*)(ws + OFF_S);
  float* HM = ws + OFF_HM;
  unsigned short* h  = (unsigned short*)(ws + OFF_H);
  unsigned short* qb = (unsigned short*)(ws + OFF_QB);
  unsigned short* dq0 = (unsigned short*)(ws + OFF_DQ0);
  unsigned short* dq1 = (unsigned short*)(ws + OFF_DQ1);
  unsigned short* A1 = (unsigned short*)(ws + OFF_A1);
  unsigned short* xp = (unsigned short*)(ws + OFF_XP);
  unsigned short* z1 = (unsigned short*)(ws + OFF_Z1);
  unsigned short* z2 = (unsigned short*)(ws + OFF_Z2);
  unsigned short* bc = (unsigned short*)(ws + OFF_BC);
  unsigned short* xa = (unsigned short*)(ws + OFF_XA);
  unsigned short* wtb = (unsigned short*)(ws + OFF_WT);

  k_preamble<<<dim3(16680), dim3(256), 0, stream>>>(x, w_in, w_hid, w_b1, w_b21, w_b22,
                                                    w_out, S, HM, wtb, h, qb, xp, cnt,
                                                    part, dx2, gf, gfc);

  dim3 sg(56, 8);
  dim3 qg(NS * NPIX / 256);
  unsigned short* dqc = dq0;
  unsigned short* dqn = dq1;
  for (int step = 0; step < 4; ++step) {
    if (step == 0)
      k_qrhs_dq<true><<<qg, dim3(256), 0, stream>>>(h, qb, dq1, dqc, ngf, gf, fdx, cc, dtf);
    else {
      k_qrhs_dq<false><<<qg, dim3(256), 0, stream>>>(h, qb, dqc, dqn, ngf, gf, fdx, cc, dtf);
      unsigned short* tmp = dqc; dqc = dqn; dqn = tmp;
    }
    k_solve<0><<<sg, dim3(512), 0, stream>>>(S, dqc, A1, HM, nullptr, nullptr, part);
    if (step < 3)
      k_solve<1><<<sg, dim3(512), 0, stream>>>(S, A1, nullptr, nullptr, x, h, part);
    else
      k_solve<2><<<sg, dim3(512), 0, stream>>>(S, A1, nullptr, nullptr, x, nullptr, part);
  }

  dim3 cg4(16, 16, 4);
  k_conv16<<<cg4, dim3(256), 0, stream>>>(xp, wtb + W_IN, b_in, z1);
  k_conv64b<false><<<cg4, dim3(512), 0, stream>>>(z1, wtb + W_HID, b_hid, z2);
  k_conv3<<<cg4, dim3(512), 0, stream>>>(z2, wtb + W_B1, wtb + W_B21, wtb + W_B22,
                                         b_b1, b_b21, b_b22, z1, bc);
  k_convout<<<cg4, dim3(512), 0, stream>>>(z1, bc, wtb + W_O1, b_out, xa);

  k_red_ae<<<dim3(1024), dim3(256), 0, stream>>>(x, xa, part, cnt, out);
}

// Round 18
// 466.953 us; speedup vs baseline: 1.1030x; 1.1030x over previous
//
#include <hip/hip_runtime.h>
#include <math.h>

#define NS 56        // B*(T-1)
#define NPIX 65536   // 256*256

static constexpr double D_PI = 3.14159265358979323846;

typedef __attribute__((ext_vector_type(8))) short short8;
typedef __attribute__((ext_vector_type(4))) float f32x4;
typedef __attribute__((ext_vector_type(16))) float f32x16;

__device__ inline unsigned short f2bf(float f) {
  union { float f; unsigned int u; } v; v.f = f;
  unsigned int r = v.u + 0x7FFFu + ((v.u >> 16) & 1u);
  return (unsigned short)(r >> 16);
}
__device__ inline float bf2f(unsigned short b) {
  union { float f; unsigned int u; } v; v.u = ((unsigned int)b) << 16;
  return v.f;
}

// ---------------- workspace layout (float offsets) ----------------
// part doubles: [0,1024) ae, [1024,1472) dyn-interior, [1472,1528) dyn-boundary
#define SLC      (NS * NPIX)
#define OFF_PART 0
#define OFF_CNT  3584
#define OFF_S    4096
#define OFF_HM   36864
#define OFF_H    102400                   // bf16 (half used)
#define OFF_QB   (OFF_H + SLC)            // bf16 (half used)
#define OFF_DQ0  (OFF_QB + SLC)
#define OFF_DQ1  (OFF_DQ0 + SLC / 2)
#define OFF_A1   (OFF_DQ1 + SLC / 2)
#define OFF_XP   (OFF_A1 + SLC / 2)
#define OFF_Z1   (OFF_XP + 2097152)
#define OFF_Z2   (OFF_Z1 + 8388608)
#define OFF_BC   (OFF_Z2 + 8388608)
#define OFF_XA   (OFF_BC + 8388608)
#define OFF_WT   (OFF_XA + 2097152)
// weight regions in SHORT offsets from wtb
#define W_IN    0
#define W_HID   10240
#define W_B1    47104
#define W_B21   83968
#define W_B22   120832
#define W_O1    157696
#define W_O2    166912

#define QCLAMP 1.0e12f
#define HCLAMP 1.0e15f

// ---------------- preamble: init + wprep + qg init + pack x + boundary-dyn ----------
__global__ __launch_bounds__(256) void k_preamble(const float* __restrict__ x,
                                                  const float* __restrict__ w_in,
                                                  const float* __restrict__ w_hid,
                                                  const float* __restrict__ w_b1,
                                                  const float* __restrict__ w_b21,
                                                  const float* __restrict__ w_b22,
                                                  const float* __restrict__ w_out,
                                                  unsigned short* __restrict__ S,
                                                  float* __restrict__ HM,
                                                  unsigned short* __restrict__ wtb,
                                                  unsigned short* __restrict__ h,
                                                  unsigned short* __restrict__ qb,
                                                  unsigned short* __restrict__ xp,
                                                  unsigned int* __restrict__ cnt,
                                                  double* __restrict__ part,
                                                  float dx2, float gf, float gfc) {
  const int blk = blockIdx.x;
  const int tid = threadIdx.x;
  if (blk < 256) {
    int idx = blk * 256 + tid;
    if (idx == 0) *cnt = 0u;
    int i = idx >> 8, j = idx & 255;
    float sv = 0.f, hv = 1.f;
    if (i < 254 && j < 254) {
      double arg = D_PI * (double)((i + 1) * (j + 1)) / 255.0;
      sv = (float)((2.0 / sqrt(510.0)) * sin(arg));
      double la = 2.0 * (cos(D_PI * (double)(i + 1) / 255.0) - 1.0) / (double)dx2
                + 2.0 * (cos(D_PI * (double)(j + 1) / 255.0) - 1.0) / (double)dx2;
      hv = (float)((9.81 / 1e-4) * la - 9.81 * 1e-4 / (2.7 * 2.7));
    }
    S[idx] = f2bf(sv);
    HM[idx] = hv;
  } else if (blk < 256 + 1008) {
    int jb = blk - 256;
    int job = jb / 144;
    int e = (jb - job * 144) * 256 + tid;
    const float* src;
    int dstOff, chunks, icpShift, icw, ic0, icReal, ocw, ocReal;
    switch (job) {
      case 0: src = w_in;  dstOff = W_IN;  chunks = 5;  icpShift = 4; icw = 15;  ic0 = 0;  icReal = 15; ocw = 64; ocReal = 64; break;
      case 1: src = w_hid; dstOff = W_HID; chunks = 18; icpShift = 6; icw = 64;  ic0 = 0;  icReal = 64; ocw = 64; ocReal = 64; break;
      case 2: src = w_b1;  dstOff = W_B1;  chunks = 18; icpShift = 6; icw = 64;  ic0 = 0;  icReal = 64; ocw = 64; ocReal = 64; break;
      case 3: src = w_b21; dstOff = W_B21; chunks = 18; icpShift = 6; icw = 64;  ic0 = 0;  icReal = 64; ocw = 64; ocReal = 64; break;
      case 4: src = w_b22; dstOff = W_B22; chunks = 18; icpShift = 6; icw = 64;  ic0 = 0;  icReal = 64; ocw = 64; ocReal = 64; break;
      case 5: src = w_out; dstOff = W_O1;  chunks = 18; icpShift = 6; icw = 128; ic0 = 0;  icReal = 64; ocw = 16; ocReal = 15; break;
      default: src = w_out; dstOff = W_O2; chunks = 18; icpShift = 6; icw = 128; ic0 = 64; icReal = 64; ocw = 16; ocReal = 15; break;
    }
    int total = chunks * 4 * ocw * 8;
    if (e < total) {
      int j = e & 7;
      int oc = (e >> 3) % ocw;
      int ckg = e / (8 * ocw);
      int kg = ckg & 3, c = ckg >> 2;
      int Kidx = c * 32 + kg * 8 + j;
      int tap = Kidx >> icpShift;
      int ic = Kidx & ((1 << icpShift) - 1);
      float v = 0.f;
      if (tap < 9 && ic < icReal && oc < ocReal)
        v = src[((size_t)oc * icw + ic0 + ic) * 9 + tap];
      wtb[dstOff + e] = f2bf(v);
    }
  } else if (blk < 256 + 1008 + 14336) {
    int idx = (blk - 1264) * 256 + tid;
    int s = idx >> 16, p = idx & 65535;
    int y = p >> 8, xx = p & 255;
    int b = s / 14, t = s - b * 14;
    const float* hb = x + (size_t)(b * 15 + t) * NPIX;
    float hc = hb[p];
    float qv;
    if (y >= 2 && y <= 252 && xx >= 2 && xx <= 252) {
      qv = gf * ((hb[p + 256] + hb[p - 256] - 2.f * hc) / dx2
               + (hb[p + 1] + hb[p - 1] - 2.f * hc) / dx2) - gfc * hc;
    } else {
      qv = -gfc * hc;
    }
    h[idx] = f2bf(hc);
    qb[idx] = f2bf(qv);
  } else if (blk < 256 + 1008 + 14336 + 1024) {
    int e = (blk - 15600) * 256 + tid;
    int b = e >> 16, p = e & 65535;
    const float* xb = x + (size_t)b * 15 * NPIX + p;
    union { unsigned short u16[16]; uint4 u4[2]; } vv;
#pragma unroll
    for (int c = 0; c < 15; ++c) vv.u16[c] = f2bf(xb[(size_t)c * NPIX]);
    vv.u16[15] = 0;
    uint4* dst = (uint4*)&xp[(size_t)e * 16];
    dst[0] = vv.u4[0];
    dst[1] = vv.u4[1];
  } else {
    // boundary dyn term (h frame == bf16(hb) forever)
    int s = blk - 16624;
    int b = s / 14, t = s - b * 14;
    const float* hb = x + (size_t)(b * 15 + t) * NPIX;
    const float* x1 = x + (size_t)(b * 15 + t + 1) * NPIX;
    double sum = 0.0;
    for (int i = tid; i < 1020; i += 256) {
      int y, xc;
      if (i < 256)      { y = 0;         xc = i; }
      else if (i < 512) { y = 255;       xc = i - 256; }
      else if (i < 766) { y = i - 511;   xc = 0; }
      else              { y = i - 765;   xc = 255; }
      int p = y * 256 + xc;
      float d = x1[p] - bf2f(f2bf(hb[p]));
      sum += (double)d * (double)d;
    }
    for (int o = 32; o > 0; o >>= 1) sum += __shfl_down(sum, o);
    __shared__ double sw[4];
    int lane = tid & 63, wid = tid >> 6;
    if (lane == 0) sw[wid] = sum;
    __syncthreads();
    if (tid == 0) part[1472 + s] = sw[0] + sw[1] + sw[2] + sw[3];
  }
}

// ---------------- qrhs delta form (bf16 h/qb), UNCONDITIONAL wrapped dq loads -------
template <bool FIRST>
__global__ __launch_bounds__(256) void k_qrhs_dq(const unsigned short* __restrict__ h,
                                                 const unsigned short* __restrict__ qbb,
                                                 const unsigned short* __restrict__ dqin,
                                                 unsigned short* __restrict__ dqout,
                                                 float ngf, float pgf, float fdx,
                                                 float cc, float dtf) {
  int idx = blockIdx.x * 256 + threadIdx.x;
  int s = idx >> 16, p = idx & 65535;
  int y = p >> 8, xx = p & 255;
  const unsigned short* H = h + (size_t)s * NPIX;
  const unsigned short* QB = qbb + (size_t)s * NPIX;
  const unsigned short* DQ = dqin + (size_t)s * NPIX;
  const int base = p - 257;
  auto dqv = [&](int d) -> float {
    if (FIRST) return 0.f;
    return bf2f(DQ[(base + d) & 65535]);
  };
  float q1mqb = 0.f;
  if (y >= 2 && y <= 252 && xx >= 2 && xx <= 252) {
    float hSW = bf2f(H[p + 255]), hS = bf2f(H[p + 256]), hSE = bf2f(H[p + 257]);
    float hNW = bf2f(H[p - 257]), hN = bf2f(H[p - 256]), hNE = bf2f(H[p - 255]);
    float hW = bf2f(H[p - 1]), hE = bf2f(H[p + 1]);
    float uA = ngf * (hSW + hS - hN - hNW) / fdx;
    float uB = ngf * (hS + hSE - hNE - hN) / fdx;
    float vA = pgf * (hE + hNE - hNW - hW) / fdx;
    float vB = pgf * (hSE + hE - hW - hSW) / fdx;
    float uT = 0.5f * (uA + uB);
    float vT = 0.5f * (vA + vB);
    float up = fmaxf(uT, 0.f), um = fminf(uT, 0.f);
    float vp = fmaxf(vT, 0.f), vm = fminf(vT, 0.f);
    float qbc = bf2f(QB[p]);
    float Q0 = qbc + dqv(0);
    float QE = bf2f(QB[p + 1]) + dqv(1), QW = bf2f(QB[p - 1]) + dqv(-1);
    float QEE = bf2f(QB[p + 2]) + dqv(2), QWW = bf2f(QB[p - 2]) + dqv(-2);
    float QS = bf2f(QB[p + 256]) + dqv(256), QN = bf2f(QB[p - 256]) + dqv(-256);
    float QSS = bf2f(QB[p + 512]) + dqv(512), QNN = bf2f(QB[p - 512]) + dqv(-512);
    float r = -up * cc * (2.f * QE + 3.f * Q0 - 6.f * QW + QWW)
            + um * cc * (QEE - 6.f * QE + 3.f * Q0 + 2.f * QW)
            - vp * cc * (2.f * QS + 3.f * Q0 - 6.f * QN + QNN)
            + vm * cc * (QSS - 6.f * QS + 3.f * Q0 + 2.f * QN);
    float q1 = Q0 + dtf * r;
    q1 = fminf(fmaxf(q1, -QCLAMP), QCLAMP);
    q1mqb = q1 - qbc;
  }
  int wy = (y == 0) ? 254 : ((y == 255) ? 255 : y - 1);
  int wx = (xx == 0) ? 254 : ((xx == 255) ? 255 : xx - 1);
  dqout[(size_t)s * NPIX + wy * 256 + wx] = f2bf(q1mqb);
}

// ---------------- solve core: acc2 = S @ (S @ X^T)^T for one (s,q,w) ----------------
__device__ inline f32x16 solve_core(const unsigned short* __restrict__ Sm,
                                    const unsigned short* __restrict__ X,
                                    unsigned short* __restrict__ Ul,
                                    int q, int w, int r31, int kh) {
  f32x16 acc;
#pragma unroll
  for (int i = 0; i < 16; ++i) acc[i] = 0.f;
  {
    const int ar = (32 * q + r31) * 256;
    const int br = (32 * w + r31) * 256;
#pragma unroll 4
    for (int kc = 0; kc < 256; kc += 16) {
      short8 a = *(const short8*)&Sm[ar + kc + kh * 8];
      short8 b = *(const short8*)&X[br + kc + kh * 8];
      acc = __builtin_amdgcn_mfma_f32_32x32x16_bf16(a, b, acc, 0, 0, 0);
    }
  }
  {
    const int col = 32 * w + r31;
    const int g = col >> 3, c7 = col & 7;
#pragma unroll
    for (int reg = 0; reg < 16; ++reg) {
      int i = (reg & 3) + 8 * (reg >> 2) + 4 * kh;
      Ul[i * 256 + (((g ^ (i & 7)) << 3) | c7)] = f2bf(acc[reg]);
    }
  }
  __syncthreads();
  f32x16 acc2;
#pragma unroll
  for (int i = 0; i < 16; ++i) acc2[i] = 0.f;
  {
    const int ar = (32 * w + r31) * 256;
    const int urow = r31 * 256;
    const int x7 = (r31 & 7);
#pragma unroll 4
    for (int kc = 0; kc < 256; kc += 16) {
      int g0 = (kc >> 3) + kh;
      short8 a = *(const short8*)&Sm[ar + kc + kh * 8];
      short8 b = *(const short8*)&Ul[urow + ((g0 ^ x7) << 3)];
      acc2 = __builtin_amdgcn_mfma_f32_32x32x16_bf16(a, b, acc2, 0, 0, 0);
    }
  }
  return acc2;
}

// ---------------- fused half-solve: one dstI2D ----------------
template <int EPI>
__global__ __launch_bounds__(512) void k_solve(const unsigned short* __restrict__ Sm,
                                               const unsigned short* __restrict__ Xb,
                                               unsigned short* __restrict__ Ob,
                                               const float* __restrict__ HM,
                                               const float* __restrict__ xin,
                                               unsigned short* __restrict__ hout,
                                               double* __restrict__ part) {
  __shared__ unsigned short Ul[32 * 256];
  const int s = blockIdx.x, q = blockIdx.y;
  const int lane = threadIdx.x & 63, w = threadIdx.x >> 6;
  const int r31 = lane & 31, kh = lane >> 5;
  f32x16 acc2 = solve_core(Sm, Xb + (size_t)s * NPIX, Ul, q, w, r31, kh);
  const int gn = 32 * q + r31;
  if (EPI == 0) {
    unsigned short* O = Ob + (size_t)s * NPIX;
#pragma unroll
    for (int reg = 0; reg < 16; ++reg) {
      int gm = 32 * w + (reg & 3) + 8 * (reg >> 2) + 4 * kh;
      O[(size_t)gm * 256 + gn] = f2bf(acc2[reg] / HM[(size_t)gm * 256 + gn]);
    }
  } else if (EPI == 1) {
    int b = s / 14, t = s - b * 14;
    const float* hb = xin + (size_t)(b * 15 + t) * NPIX;
    unsigned short* H = hout + (size_t)s * NPIX;
    if (gn < 254) {
#pragma unroll
      for (int reg = 0; reg < 16; ++reg) {
        int gm = 32 * w + (reg & 3) + 8 * (reg >> 2) + 4 * kh;
        if (gm < 254) {
          size_t o = (size_t)(gm + 1) * 256 + (gn + 1);
          float hv = acc2[reg] + hb[o];
          H[o] = f2bf(fminf(fmaxf(hv, -HCLAMP), HCLAMP));
        }
      }
    }
  } else {
    int b = s / 14, t = s - b * 14;
    const float* hb = xin + (size_t)(b * 15 + t) * NPIX;
    const float* x1 = xin + (size_t)(b * 15 + t + 1) * NPIX;
    double dsum = 0.0;
    if (gn < 254) {
#pragma unroll
      for (int reg = 0; reg < 16; ++reg) {
        int gm = 32 * w + (reg & 3) + 8 * (reg >> 2) + 4 * kh;
        if (gm < 254) {
          size_t o = (size_t)(gm + 1) * 256 + (gn + 1);
          float hv = acc2[reg] + hb[o];
          hv = fminf(fmaxf(hv, -HCLAMP), HCLAMP);
          float d = x1[o] - hv;
          dsum += (double)d * (double)d;
        }
      }
    }
    for (int o = 32; o > 0; o >>= 1) dsum += __shfl_down(dsum, o);
    __shared__ double sred[8];
    if (lane == 0) sred[w] = dsum;
    __syncthreads();
    if (threadIdx.x == 0) {
      double t8 = 0.0;
#pragma unroll
      for (int i = 0; i < 8; ++i) t8 += sred[i];
      part[1024 + s * 8 + q] = t8;
    }
  }
}

// ---------------- conv64, 512 thr: 8 waves = 4 rowgroups x 2 oc-halves ----------------
template <bool RELU>
__global__ __launch_bounds__(512) void k_conv64b(const unsigned short* __restrict__ in,
                                                 const unsigned short* __restrict__ wt,
                                                 const float* __restrict__ bias,
                                                 unsigned short* __restrict__ out) {
  __shared__ unsigned short tile[324 * 64];
  const int tid = threadIdx.x;
  const int lane = tid & 63, wave = tid >> 6;
  const int cl = lane & 15, kg = lane >> 4;
  const int wrow = wave & 3, wh = wave >> 2;
  const int b = blockIdx.z;
  const int gx0 = blockIdx.x * 16, gy0 = blockIdx.y * 16;

  f32x4 acc[4][2];
#pragma unroll
  for (int j = 0; j < 2; ++j) {
    float bv = bias[wh * 32 + j * 16 + cl];
#pragma unroll
    for (int i = 0; i < 4; ++i) acc[i][j] = (f32x4){bv, bv, bv, bv};
  }

  const unsigned short* inb = in + (size_t)b * NPIX * 64;
  for (int c = tid; c < 2592; c += 512) {
    int pp = c >> 3, g = c & 7;
    int ly = pp / 18, lx = pp - ly * 18;
    int iy = gy0 + ly - 1, ix = gx0 + lx - 1;
    uint4 v = make_uint4(0u, 0u, 0u, 0u);
    if (iy >= 0 && iy < 256 && ix >= 0 && ix < 256)
      v = *(const uint4*)&inb[((size_t)iy * 256 + ix) * 64 + g * 8];
    int sw = g ^ (pp & 7);
    *(uint4*)&tile[pp * 64 + sw * 8] = v;
  }
  __syncthreads();

#pragma unroll 3
  for (int cm = 0; cm < 18; ++cm) {
    const int tap = cm >> 1;
    const int g = (cm & 1) * 4 + kg;
    const int dy = tap / 3, dxx = tap - dy * 3;
    short8 bfr[2];
#pragma unroll
    for (int j = 0; j < 2; ++j)
      bfr[j] = *(const short8*)&wt[(((size_t)cm * 4 + kg) * 64 + wh * 32 + j * 16 + cl) * 8];
    const int tc = cl + dxx;
#pragma unroll
    for (int i = 0; i < 4; ++i) {
      int pp = (wrow * 4 + i + dy) * 18 + tc;
      int g2 = g ^ (pp & 7);
      short8 av = *(const short8*)&tile[pp * 64 + g2 * 8];
#pragma unroll
      for (int j = 0; j < 2; ++j)
        acc[i][j] = __builtin_amdgcn_mfma_f32_16x16x32_bf16(av, bfr[j], acc[i][j], 0, 0, 0);
    }
  }

  const size_t outBase = (size_t)b * NPIX * 64;
#pragma unroll
  for (int i = 0; i < 4; ++i) {
    int y = gy0 + wrow * 4 + i;
#pragma unroll
    for (int j = 0; j < 2; ++j) {
      int oc = wh * 32 + j * 16 + cl;
#pragma unroll
      for (int r = 0; r < 4; ++r) {
        int px = gx0 + kg * 4 + r;
        size_t oi = outBase + ((size_t)y * 256 + px) * 64 + oc;
        float v = acc[i][j][r];
        if (RELU) v = fmaxf(v, 0.f);
        out[oi] = f2bf(v);
      }
    }
  }
}

// ---------------- k_conv3: stage z2 once; b1 -> z1out, then b21*b22 -> bc ----------
__global__ __launch_bounds__(512) void k_conv3(const unsigned short* __restrict__ in,
                                               const unsigned short* __restrict__ wt1,
                                               const unsigned short* __restrict__ wtA,
                                               const unsigned short* __restrict__ wtB,
                                               const float* __restrict__ bias1,
                                               const float* __restrict__ biasA,
                                               const float* __restrict__ biasB,
                                               unsigned short* __restrict__ out1,
                                               unsigned short* __restrict__ outm) {
  __shared__ unsigned short tile[324 * 64];
  const int tid = threadIdx.x;
  const int lane = tid & 63, wave = tid >> 6;
  const int cl = lane & 15, kg = lane >> 4;
  const int wrow = wave & 3, wh = wave >> 2;
  const int b = blockIdx.z;
  const int gx0 = blockIdx.x * 16, gy0 = blockIdx.y * 16;
  const size_t outBase = (size_t)b * NPIX * 64;

  // ---- stage z2 tile once ----
  const unsigned short* inb = in + (size_t)b * NPIX * 64;
  for (int c = tid; c < 2592; c += 512) {
    int pp = c >> 3, g = c & 7;
    int ly = pp / 18, lx = pp - ly * 18;
    int iy = gy0 + ly - 1, ix = gx0 + lx - 1;
    uint4 v = make_uint4(0u, 0u, 0u, 0u);
    if (iy >= 0 && iy < 256 && ix >= 0 && ix < 256)
      v = *(const uint4*)&inb[((size_t)iy * 256 + ix) * 64 + g * 8];
    int sw = g ^ (pp & 7);
    *(uint4*)&tile[pp * 64 + sw * 8] = v;
  }
  __syncthreads();

  // ---- phase 1: b1 conv ----
  {
    f32x4 acc[4][2];
#pragma unroll
    for (int j = 0; j < 2; ++j) {
      float bv = bias1[wh * 32 + j * 16 + cl];
#pragma unroll
      for (int i = 0; i < 4; ++i) acc[i][j] = (f32x4){bv, bv, bv, bv};
    }
#pragma unroll 3
    for (int cm = 0; cm < 18; ++cm) {
      const int tap = cm >> 1;
      const int g = (cm & 1) * 4 + kg;
      const int dy = tap / 3, dxx = tap - dy * 3;
      short8 bfr[2];
#pragma unroll
      for (int j = 0; j < 2; ++j)
        bfr[j] = *(const short8*)&wt1[(((size_t)cm * 4 + kg) * 64 + wh * 32 + j * 16 + cl) * 8];
      const int tc = cl + dxx;
#pragma unroll
      for (int i = 0; i < 4; ++i) {
        int pp = (wrow * 4 + i + dy) * 18 + tc;
        int g2 = g ^ (pp & 7);
        short8 av = *(const short8*)&tile[pp * 64 + g2 * 8];
#pragma unroll
        for (int j = 0; j < 2; ++j)
          acc[i][j] = __builtin_amdgcn_mfma_f32_16x16x32_bf16(av, bfr[j], acc[i][j], 0, 0, 0);
      }
    }
#pragma unroll
    for (int i = 0; i < 4; ++i) {
      int y = gy0 + wrow * 4 + i;
#pragma unroll
      for (int j = 0; j < 2; ++j) {
        int oc = wh * 32 + j * 16 + cl;
#pragma unroll
        for (int r = 0; r < 4; ++r) {
          int px = gx0 + kg * 4 + r;
          out1[outBase + ((size_t)y * 256 + px) * 64 + oc] = f2bf(acc[i][j][r]);
        }
      }
    }
  }

  // ---- phase 2: b21 and b22 convs, write product ----
  {
    f32x4 accA[4][2], accB[4][2];
#pragma unroll
    for (int j = 0; j < 2; ++j) {
      float ba = biasA[wh * 32 + j * 16 + cl], bb = biasB[wh * 32 + j * 16 + cl];
#pragma unroll
      for (int i = 0; i < 4; ++i) {
        accA[i][j] = (f32x4){ba, ba, ba, ba};
        accB[i][j] = (f32x4){bb, bb, bb, bb};
      }
    }
#pragma unroll 2
    for (int cm = 0; cm < 18; ++cm) {
      const int tap = cm >> 1;
      const int g = (cm & 1) * 4 + kg;
      const int dy = tap / 3, dxx = tap - dy * 3;
      const int tc = cl + dxx;
      short8 wa[2], wb[2];
#pragma unroll
      for (int j = 0; j < 2; ++j) {
        wa[j] = *(const short8*)&wtA[(((size_t)cm * 4 + kg) * 64 + wh * 32 + j * 16 + cl) * 8];
        wb[j] = *(const short8*)&wtB[(((size_t)cm * 4 + kg) * 64 + wh * 32 + j * 16 + cl) * 8];
      }
#pragma unroll
      for (int i = 0; i < 4; ++i) {
        int pp = (wrow * 4 + i + dy) * 18 + tc;
        int g2 = g ^ (pp & 7);
        short8 av = *(const short8*)&tile[pp * 64 + g2 * 8];
#pragma unroll
        for (int j = 0; j < 2; ++j) {
          accA[i][j] = __builtin_amdgcn_mfma_f32_16x16x32_bf16(av, wa[j], accA[i][j], 0, 0, 0);
          accB[i][j] = __builtin_amdgcn_mfma_f32_16x16x32_bf16(av, wb[j], accB[i][j], 0, 0, 0);
        }
      }
    }
#pragma unroll
    for (int i = 0; i < 4; ++i) {
      int y = gy0 + wrow * 4 + i;
#pragma unroll
      for (int j = 0; j < 2; ++j) {
        int oc = wh * 32 + j * 16 + cl;
#pragma unroll
        for (int r = 0; r < 4; ++r) {
          int px = gx0 + kg * 4 + r;
          outm[outBase + ((size_t)y * 256 + px) * 64 + oc] = f2bf(accA[i][j][r] * accB[i][j][r]);
        }
      }
    }
  }
}

// ---------------- out conv: dual source, 16 oc, 512 thr (2 rows/wave) -------------
__global__ __launch_bounds__(512) void k_convout(const unsigned short* __restrict__ in0,
                                                 const unsigned short* __restrict__ in1,
                                                 const unsigned short* __restrict__ wt,
                                                 const float* __restrict__ bias,
                                                 unsigned short* __restrict__ out) {
  __shared__ unsigned short tile[324 * 64];
  const int tid = threadIdx.x;
  const int lane = tid & 63, wave = tid >> 6;
  const int cl = lane & 15, kg = lane >> 4;
  const int b = blockIdx.z;
  const int gx0 = blockIdx.x * 16, gy0 = blockIdx.y * 16;

  f32x4 acc[2];
  {
    float bv = (cl < 15) ? bias[cl] : 0.f;
    acc[0] = (f32x4){bv, bv, bv, bv};
    acc[1] = acc[0];
  }

  for (int src = 0; src < 2; ++src) {
    const unsigned short* inb = (src ? in1 : in0) + (size_t)b * NPIX * 64;
    const unsigned short* wtp = wt + src * 9216;
    if (src) __syncthreads();
    for (int c = tid; c < 2592; c += 512) {
      int pp = c >> 3, g = c & 7;
      int ly = pp / 18, lx = pp - ly * 18;
      int iy = gy0 + ly - 1, ix = gx0 + lx - 1;
      uint4 v = make_uint4(0u, 0u, 0u, 0u);
      if (iy >= 0 && iy < 256 && ix >= 0 && ix < 256)
        v = *(const uint4*)&inb[((size_t)iy * 256 + ix) * 64 + g * 8];
      int sw = g ^ (pp & 7);
      *(uint4*)&tile[pp * 64 + sw * 8] = v;
    }
    __syncthreads();
#pragma unroll 3
    for (int cm = 0; cm < 18; ++cm) {
      const int tap = cm >> 1;
      const int g = (cm & 1) * 4 + kg;
      const int dy = tap / 3, dxx = tap - dy * 3;
      short8 bfr = *(const short8*)&wtp[(((size_t)cm * 4 + kg) * 16 + cl) * 8];
      const int tc = cl + dxx;
#pragma unroll
      for (int i = 0; i < 2; ++i) {
        int pp = (wave * 2 + i + dy) * 18 + tc;
        int g2 = g ^ (pp & 7);
        short8 av = *(const short8*)&tile[pp * 64 + g2 * 8];
        acc[i] = __builtin_amdgcn_mfma_f32_16x16x32_bf16(av, bfr, acc[i], 0, 0, 0);
      }
    }
  }

  const size_t outBase = (size_t)b * NPIX * 16;
#pragma unroll
  for (int i = 0; i < 2; ++i) {
    int y = gy0 + wave * 2 + i;
#pragma unroll
    for (int r = 0; r < 4; ++r) {
      int px = gx0 + kg * 4 + r;
      size_t oi = outBase + ((size_t)y * 256 + px) * 16 + cl;
      out[oi] = f2bf(acc[i][r]);
    }
  }
}

// ---------------- conv16 (conv_in), 256 thr ----------------
__global__ __launch_bounds__(256) void k_conv16(const unsigned short* __restrict__ in,
                                                const unsigned short* __restrict__ wt,
                                                const float* __restrict__ bias,
                                                unsigned short* __restrict__ out) {
  __shared__ unsigned short wlds[10240];
  __shared__ unsigned short tile[324 * 16];

  const int tid = threadIdx.x;
  const int lane = tid & 63, wave = tid >> 6;
  const int cl = lane & 15, kg = lane >> 4;
  const int b = blockIdx.z;
  const int gx0 = blockIdx.x * 16, gy0 = blockIdx.y * 16;

  {
    uint4* wl = (uint4*)wlds;
    const uint4* wg = (const uint4*)wt;
    for (int i = tid; i < 1280; i += 256) wl[i] = wg[i];
  }
  const unsigned short* inb = in + (size_t)b * NPIX * 16;
  for (int c = tid; c < 648; c += 256) {
    int pp = c >> 1, g = c & 1;
    int ly = pp / 18, lx = pp - ly * 18;
    int iy = gy0 + ly - 1, ix = gx0 + lx - 1;
    uint4 v = make_uint4(0u, 0u, 0u, 0u);
    if (iy >= 0 && iy < 256 && ix >= 0 && ix < 256)
      v = *(const uint4*)&inb[((size_t)iy * 256 + ix) * 16 + g * 8];
    int sw = g ^ (pp & 1);
    *(uint4*)&tile[pp * 16 + sw * 8] = v;
  }
  __syncthreads();

  f32x4 acc[4][4];
#pragma unroll
  for (int j = 0; j < 4; ++j) {
    float bv = bias[j * 16 + cl];
#pragma unroll
    for (int i = 0; i < 4; ++i) acc[i][j] = (f32x4){bv, bv, bv, bv};
  }

#pragma unroll
  for (int c = 0; c < 5; ++c) {
    int tap = 2 * c + (kg >> 1);
    int dy = tap / 3, dxx = tap - dy * 3;
    int gidx = kg & 1;
    short8 bfr[4];
#pragma unroll
    for (int j = 0; j < 4; ++j)
      bfr[j] = *(const short8*)&wlds[((c * 4 + kg) * 64 + j * 16 + cl) * 8];
    int tc = cl + dxx;
#pragma unroll
    for (int i = 0; i < 4; ++i) {
      int tr = wave * 4 + i + dy;
      if (tr > 17) tr = 17;
      int pp = tr * 18 + tc;
      int g2 = gidx ^ (pp & 1);
      short8 av = *(const short8*)&tile[pp * 16 + g2 * 8];
#pragma unroll
      for (int j = 0; j < 4; ++j)
        acc[i][j] = __builtin_amdgcn_mfma_f32_16x16x32_bf16(av, bfr[j], acc[i][j], 0, 0, 0);
    }
  }

  const size_t outBase = (size_t)b * NPIX * 64;
#pragma unroll
  for (int i = 0; i < 4; ++i) {
    int y = gy0 + wave * 4 + i;
#pragma unroll
    for (int j = 0; j < 4; ++j) {
      int oc = j * 16 + cl;
#pragma unroll
      for (int r = 0; r < 4; ++r) {
        int px = gx0 + kg * 4 + r;
        size_t oi = outBase + ((size_t)y * 256 + px) * 64 + oc;
        out[oi] = f2bf(fmaxf(acc[i][j][r], 0.f));
      }
    }
  }
}

// ---------------- ae reduction (coalesced) + ticket final ----------------
__global__ __launch_bounds__(256) void k_red_ae(const float* __restrict__ x,
                                                const unsigned short* __restrict__ xa,
                                                double* __restrict__ part,
                                                unsigned int* __restrict__ cnt,
                                                float* __restrict__ out) {
  const int NBT = 1024;
  const int bid = blockIdx.x;
  const int tid = threadIdx.x;
  const int e = bid * 256 + tid;
  const int b = e >> 16, p = e & 65535;
  union { unsigned short u16[16]; uint4 u4[2]; } vv;
  const uint4* xap = (const uint4*)&xa[(size_t)e * 16];
  vv.u4[0] = xap[0];
  vv.u4[1] = xap[1];
  const float* xb = x + (size_t)b * 15 * NPIX + p;
  double sum = 0.0;
#pragma unroll
  for (int c = 0; c < 15; ++c) {
    float d = xb[(size_t)c * NPIX] - bf2f(vv.u16[c]);
    sum += (double)d * (double)d;
  }
  for (int o = 32; o > 0; o >>= 1) sum += __shfl_down(sum, o);
  __shared__ double sw[4];
  __shared__ bool last;
  int lane = tid & 63, wid = tid >> 6;
  if (lane == 0) sw[wid] = sum;
  __syncthreads();
  if (tid == 0) {
    part[bid] = sw[0] + sw[1] + sw[2] + sw[3];
    __threadfence();
    unsigned int t = atomicAdd(cnt, 1u);
    last = (t == (unsigned)(NBT - 1));
  }
  __syncthreads();
  if (last) {
    __threadfence();
    double s1 = 0.0, s2 = 0.0;
    for (int i = tid; i < 504; i += 256) s1 += part[1024 + i];
    for (int i = tid; i < NBT; i += 256) s2 += part[i];
    for (int o = 32; o > 0; o >>= 1) {
      s1 += __shfl_down(s1, o);
      s2 += __shfl_down(s2, o);
    }
    __shared__ double a1[4], a2[4];
    if (lane == 0) { a1[wid] = s1; a2[wid] = s2; }
    __syncthreads();
    if (tid == 0) {
      double v = (a1[0] + a1[1] + a1[2] + a1[3]) / (double)(NS * NPIX)
               + (a2[0] + a2[1] + a2[2] + a2[3]) / (double)(60 * NPIX);
      if (!(v == v)) v = 0.0;
      if (v > 1.0e30) v = 1.0e30;
      if (v < -1.0e30) v = -1.0e30;
      out[0] = (float)v;
    }
  }
}

// ---------------- launcher ----------------
extern "C" void kernel_launch(void* const* d_in, const int* in_sizes, int n_in,
                              void* d_out, int out_size, void* d_ws, size_t ws_size,
                              hipStream_t stream) {
  (void)in_sizes; (void)n_in; (void)out_size; (void)ws_size;
  const float* x     = (const float*)d_in[0];
  const float* w_in  = (const float*)d_in[1];
  const float* b_in  = (const float*)d_in[2];
  const float* w_hid = (const float*)d_in[3];
  const float* b_hid = (const float*)d_in[4];
  const float* w_b1  = (const float*)d_in[5];
  const float* b_b1  = (const float*)d_in[6];
  const float* w_b21 = (const float*)d_in[7];
  const float* b_b21 = (const float*)d_in[8];
  const float* w_b22 = (const float*)d_in[9];
  const float* b_b22 = (const float*)d_in[10];
  const float* w_out = (const float*)d_in[11];
  const float* b_out = (const float*)d_in[12];
  float* ws = (float*)d_ws;
  float* out = (float*)d_out;

  double mc = 0.0;
  for (int k = 0; k < 256; ++k) mc += cos((32.0 + 0.05 * k) * D_PI / 180.0);
  mc /= 256.0;
  float DXf = (float)(0.5 * (5550.0 + 5550.0 * mc));
  float dx2 = DXf * DXf;
  float gf  = (float)(9.81 / 1e-4);
  float ngf = (float)(-9.81 / 1e-4);
  float gfc = (float)(9.81 * 1e-4 / (2.7 * 2.7));
  float fdx = 4.0f * DXf;
  float cc  = 1.0f / (6.0f * DXf);
  float dtf = 21600.0f;

  double* part = (double*)d_ws;
  unsigned int* cnt = (unsigned int*)(ws + OFF_CNT);
  unsigned short* S  = (unsigned short*)(ws + OFF_S);
  float* HM = ws + OFF_HM;
  unsigned short* h  = (unsigned short*)(ws + OFF_H);
  unsigned short* qb = (unsigned short*)(ws + OFF_QB);
  unsigned short* dq0 = (unsigned short*)(ws + OFF_DQ0);
  unsigned short* dq1 = (unsigned short*)(ws + OFF_DQ1);
  unsigned short* A1 = (unsigned short*)(ws + OFF_A1);
  unsigned short* xp = (unsigned short*)(ws + OFF_XP);
  unsigned short* z1 = (unsigned short*)(ws + OFF_Z1);
  unsigned short* z2 = (unsigned short*)(ws + OFF_Z2);
  unsigned short* bc = (unsigned short*)(ws + OFF_BC);
  unsigned short* xa = (unsigned short*)(ws + OFF_XA);
  unsigned short* wtb = (unsigned short*)(ws + OFF_WT);

  k_preamble<<<dim3(16680), dim3(256), 0, stream>>>(x, w_in, w_hid, w_b1, w_b21, w_b22,
                                                    w_out, S, HM, wtb, h, qb, xp, cnt,
                                                    part, dx2, gf, gfc);

  dim3 sg(56, 8);
  dim3 qg(NS * NPIX / 256);
  unsigned short* dqc = dq0;
  unsigned short* dqn = dq1;
  for (int step = 0; step < 4; ++step) {
    if (step == 0)
      k_qrhs_dq<true><<<qg, dim3(256), 0, stream>>>(h, qb, dq1, dqc, ngf, gf, fdx, cc, dtf);
    else {
      k_qrhs_dq<false><<<qg, dim3(256), 0, stream>>>(h, qb, dqc, dqn, ngf, gf, fdx, cc, dtf);
      unsigned short* tmp = dqc; dqc = dqn; dqn = tmp;
    }
    k_solve<0><<<sg, dim3(512), 0, stream>>>(S, dqc, A1, HM, nullptr, nullptr, part);
    if (step < 3)
      k_solve<1><<<sg, dim3(512), 0, stream>>>(S, A1, nullptr, nullptr, x, h, part);
    else
      k_solve<2><<<sg, dim3(512), 0, stream>>>(S, A1, nullptr, nullptr, x, nullptr, part);
  }

  dim3 cg4(16, 16, 4);
  k_conv16<<<cg4, dim3(256), 0, stream>>>(xp, wtb + W_IN, b_in, z1);
  k_conv64b<false><<<cg4, dim3(512), 0, stream>>>(z1, wtb + W_HID, b_hid, z2);
  k_conv3<<<cg4, dim3(512), 0, stream>>>(z2, wtb + W_B1, wtb + W_B21, wtb + W_B22,
                                         b_b1, b_b21, b_b22, z1, bc);
  k_convout<<<cg4, dim3(512), 0, stream>>>(z1, bc, wtb + W_O1, b_out, xa);

  k_red_ae<<<dim3(1024), dim3(256), 0, stream>>>(x, xa, part, cnt, out);
}

// Round 19
// 452.833 us; speedup vs baseline: 1.1374x; 1.0312x over previous
//
#include <hip/hip_runtime.h>
#include <math.h>

#define NS 56        // B*(T-1)
#define NPIX 65536   // 256*256

static constexpr double D_PI = 3.14159265358979323846;

typedef __attribute__((ext_vector_type(8))) short short8;
typedef __attribute__((ext_vector_type(4))) float f32x4;
typedef __attribute__((ext_vector_type(16))) float f32x16;

__device__ inline unsigned short f2bf(float f) {
  union { float f; unsigned int u; } v; v.f = f;
  unsigned int r = v.u + 0x7FFFu + ((v.u >> 16) & 1u);
  return (unsigned short)(r >> 16);
}
__device__ inline float bf2f(unsigned short b) {
  union { float f; unsigned int u; } v; v.u = ((unsigned int)b) << 16;
  return v.f;
}

// ---------------- workspace layout (float offsets) ----------------
// part doubles: [0,1024) ae, [1024,1472) dyn-interior, [1472,1528) dyn-boundary
#define SLC      (NS * NPIX)
#define OFF_PART 0
#define OFF_CNT  3584
#define OFF_S    4096
#define OFF_HM   36864
#define OFF_H    102400                   // bf16 (half used)
#define OFF_QB   (OFF_H + SLC)            // bf16 (half used)
#define OFF_DQ0  (OFF_QB + SLC)
#define OFF_DQ1  (OFF_DQ0 + SLC / 2)
#define OFF_A1   (OFF_DQ1 + SLC / 2)
#define OFF_XP   (OFF_A1 + SLC / 2)
#define OFF_Z1   (OFF_XP + 2097152)
#define OFF_Z2   (OFF_Z1 + 8388608)
#define OFF_BC   (OFF_Z2 + 8388608)
#define OFF_XA   (OFF_BC + 8388608)
#define OFF_WT   (OFF_XA + 2097152)
// weight regions in SHORT offsets from wtb
#define W_IN    0
#define W_HID   10240
#define W_B1    47104
#define W_B21   83968
#define W_B22   120832
#define W_O1    157696
#define W_O2    166912

#define QCLAMP 1.0e12f
#define HCLAMP 1.0e15f

// ---------------- preamble: init + wprep + qg init + pack x + boundary-dyn ----------
__global__ __launch_bounds__(256) void k_preamble(const float* __restrict__ x,
                                                  const float* __restrict__ w_in,
                                                  const float* __restrict__ w_hid,
                                                  const float* __restrict__ w_b1,
                                                  const float* __restrict__ w_b21,
                                                  const float* __restrict__ w_b22,
                                                  const float* __restrict__ w_out,
                                                  unsigned short* __restrict__ S,
                                                  float* __restrict__ HM,
                                                  unsigned short* __restrict__ wtb,
                                                  unsigned short* __restrict__ h,
                                                  unsigned short* __restrict__ qb,
                                                  unsigned short* __restrict__ xp,
                                                  unsigned int* __restrict__ cnt,
                                                  double* __restrict__ part,
                                                  float dx2, float gf, float gfc) {
  const int blk = blockIdx.x;
  const int tid = threadIdx.x;
  if (blk < 256) {
    int idx = blk * 256 + tid;
    if (idx == 0) *cnt = 0u;
    int i = idx >> 8, j = idx & 255;
    float sv = 0.f, hv = 1.f;
    if (i < 254 && j < 254) {
      double arg = D_PI * (double)((i + 1) * (j + 1)) / 255.0;
      sv = (float)((2.0 / sqrt(510.0)) * sin(arg));
      double la = 2.0 * (cos(D_PI * (double)(i + 1) / 255.0) - 1.0) / (double)dx2
                + 2.0 * (cos(D_PI * (double)(j + 1) / 255.0) - 1.0) / (double)dx2;
      hv = (float)((9.81 / 1e-4) * la - 9.81 * 1e-4 / (2.7 * 2.7));
    }
    S[idx] = f2bf(sv);
    HM[idx] = hv;
  } else if (blk < 256 + 1008) {
    int jb = blk - 256;
    int job = jb / 144;
    int e = (jb - job * 144) * 256 + tid;
    const float* src;
    int dstOff, chunks, icpShift, icw, ic0, icReal, ocw, ocReal;
    switch (job) {
      case 0: src = w_in;  dstOff = W_IN;  chunks = 5;  icpShift = 4; icw = 15;  ic0 = 0;  icReal = 15; ocw = 64; ocReal = 64; break;
      case 1: src = w_hid; dstOff = W_HID; chunks = 18; icpShift = 6; icw = 64;  ic0 = 0;  icReal = 64; ocw = 64; ocReal = 64; break;
      case 2: src = w_b1;  dstOff = W_B1;  chunks = 18; icpShift = 6; icw = 64;  ic0 = 0;  icReal = 64; ocw = 64; ocReal = 64; break;
      case 3: src = w_b21; dstOff = W_B21; chunks = 18; icpShift = 6; icw = 64;  ic0 = 0;  icReal = 64; ocw = 64; ocReal = 64; break;
      case 4: src = w_b22; dstOff = W_B22; chunks = 18; icpShift = 6; icw = 64;  ic0 = 0;  icReal = 64; ocw = 64; ocReal = 64; break;
      case 5: src = w_out; dstOff = W_O1;  chunks = 18; icpShift = 6; icw = 128; ic0 = 0;  icReal = 64; ocw = 16; ocReal = 15; break;
      default: src = w_out; dstOff = W_O2; chunks = 18; icpShift = 6; icw = 128; ic0 = 64; icReal = 64; ocw = 16; ocReal = 15; break;
    }
    int total = chunks * 4 * ocw * 8;
    if (e < total) {
      int j = e & 7;
      int oc = (e >> 3) % ocw;
      int ckg = e / (8 * ocw);
      int kg = ckg & 3, c = ckg >> 2;
      int Kidx = c * 32 + kg * 8 + j;
      int tap = Kidx >> icpShift;
      int ic = Kidx & ((1 << icpShift) - 1);
      float v = 0.f;
      if (tap < 9 && ic < icReal && oc < ocReal)
        v = src[((size_t)oc * icw + ic0 + ic) * 9 + tap];
      wtb[dstOff + e] = f2bf(v);
    }
  } else if (blk < 256 + 1008 + 14336) {
    int idx = (blk - 1264) * 256 + tid;
    int s = idx >> 16, p = idx & 65535;
    int y = p >> 8, xx = p & 255;
    int b = s / 14, t = s - b * 14;
    const float* hb = x + (size_t)(b * 15 + t) * NPIX;
    float hc = hb[p];
    float qv;
    if (y >= 2 && y <= 252 && xx >= 2 && xx <= 252) {
      qv = gf * ((hb[p + 256] + hb[p - 256] - 2.f * hc) / dx2
               + (hb[p + 1] + hb[p - 1] - 2.f * hc) / dx2) - gfc * hc;
    } else {
      qv = -gfc * hc;
    }
    h[idx] = f2bf(hc);
    qb[idx] = f2bf(qv);
  } else if (blk < 256 + 1008 + 14336 + 1024) {
    int e = (blk - 15600) * 256 + tid;
    int b = e >> 16, p = e & 65535;
    const float* xb = x + (size_t)b * 15 * NPIX + p;
    union { unsigned short u16[16]; uint4 u4[2]; } vv;
#pragma unroll
    for (int c = 0; c < 15; ++c) vv.u16[c] = f2bf(xb[(size_t)c * NPIX]);
    vv.u16[15] = 0;
    uint4* dst = (uint4*)&xp[(size_t)e * 16];
    dst[0] = vv.u4[0];
    dst[1] = vv.u4[1];
  } else {
    // boundary dyn term (h frame == bf16(hb) forever)
    int s = blk - 16624;
    int b = s / 14, t = s - b * 14;
    const float* hb = x + (size_t)(b * 15 + t) * NPIX;
    const float* x1 = x + (size_t)(b * 15 + t + 1) * NPIX;
    double sum = 0.0;
    for (int i = tid; i < 1020; i += 256) {
      int y, xc;
      if (i < 256)      { y = 0;         xc = i; }
      else if (i < 512) { y = 255;       xc = i - 256; }
      else if (i < 766) { y = i - 511;   xc = 0; }
      else              { y = i - 765;   xc = 255; }
      int p = y * 256 + xc;
      float d = x1[p] - bf2f(f2bf(hb[p]));
      sum += (double)d * (double)d;
    }
    for (int o = 32; o > 0; o >>= 1) sum += __shfl_down(sum, o);
    __shared__ double sw[4];
    int lane = tid & 63, wid = tid >> 6;
    if (lane == 0) sw[wid] = sum;
    __syncthreads();
    if (tid == 0) part[1472 + s] = sw[0] + sw[1] + sw[2] + sw[3];
  }
}

// ---------------- qrhs delta form, VECTORIZED: 1 thread = 8-px aligned out segment --
// Output segment base o (multiple of 8) in shifted dq layout; pixels y=wy+1,
// xx=wx0+1..wx0+8. All stencil reads are aligned short8 window loads; dq window
// bases wrap via &65535 into the structural-zero pad rows. Per-element interior
// mask; all speculative loads hit initialized finite buffers.
template <bool FIRST>
__global__ __launch_bounds__(256) void k_qrhs_v8(const unsigned short* __restrict__ h,
                                                 const unsigned short* __restrict__ qbb,
                                                 const unsigned short* __restrict__ dqin,
                                                 unsigned short* __restrict__ dqout,
                                                 float ngf, float pgf, float fdx,
                                                 float cc, float dtf) {
  const int idx = blockIdx.x * 256 + threadIdx.x;   // 1792 blocks
  const int s = idx >> 13;                          // 8192 threads per slice
  const int o = (idx & 8191) * 8;                   // output base within slice
  const int wy = o >> 8, wx0 = o & 255;
  unsigned short* OUT = dqout + (size_t)s * NPIX + o;
  if (wy < 1 || wy > 251) {                         // y outside [2,252]: all zeros
    *(short8*)OUT = (short8){0, 0, 0, 0, 0, 0, 0, 0};
    return;
  }
  const int pb = o + 256;                           // = y*256 + wx0
  const unsigned short* H = h + (size_t)s * NPIX;
  const unsigned short* QB = qbb + (size_t)s * NPIX;
  const unsigned short* DQ = dqin + (size_t)s * NPIX;

  union U16 { short8 s2[2]; unsigned short u[16]; };
  union U24 { short8 s3[3]; unsigned short u[24]; };

  U16 hN, hC, hS;
  hN.s2[0] = *(const short8*)&H[pb - 256]; hN.s2[1] = *(const short8*)&H[pb - 248];
  hC.s2[0] = *(const short8*)&H[pb];       hC.s2[1] = *(const short8*)&H[pb + 8];
  hS.s2[0] = *(const short8*)&H[pb + 256]; hS.s2[1] = *(const short8*)&H[pb + 264];

  U24 qC;
  qC.s3[0] = *(const short8*)&QB[pb - 8];
  qC.s3[1] = *(const short8*)&QB[pb];
  qC.s3[2] = *(const short8*)&QB[pb + 8];
  U16 qN, qS, qNN, qSS;
  qN.s2[0]  = *(const short8*)&QB[pb - 256]; qN.s2[1]  = *(const short8*)&QB[pb - 248];
  qS.s2[0]  = *(const short8*)&QB[pb + 256]; qS.s2[1]  = *(const short8*)&QB[pb + 264];
  qNN.s2[0] = *(const short8*)&QB[pb - 512]; qNN.s2[1] = *(const short8*)&QB[pb - 504];
  qSS.s2[0] = *(const short8*)&QB[pb + 512]; qSS.s2[1] = *(const short8*)&QB[pb + 520];

  U24 dC;
  U16 dN, dS, dNN, dSS;
  if (!FIRST) {
    dC.s3[0] = *(const short8*)&DQ[(o - 8) & 65535];
    dC.s3[1] = *(const short8*)&DQ[o];
    dC.s3[2] = *(const short8*)&DQ[(o + 8) & 65535];
    dN.s2[0]  = *(const short8*)&DQ[(o - 256) & 65535];
    dS.s2[0]  = *(const short8*)&DQ[(o + 256) & 65535];
    dNN.s2[0] = *(const short8*)&DQ[(o - 512) & 65535];
    dSS.s2[0] = *(const short8*)&DQ[(o + 512) & 65535];
  }

  union { unsigned short u[8]; short8 s; } res;
#pragma unroll
  for (int j = 0; j < 8; ++j) {
    const int xxj = wx0 + 1 + j;
    float val = 0.f;
    if (xxj >= 2 && xxj <= 252) {
      float hNW = bf2f(hN.u[j]), hNc = bf2f(hN.u[j + 1]), hNE = bf2f(hN.u[j + 2]);
      float hW  = bf2f(hC.u[j]),                           hE  = bf2f(hC.u[j + 2]);
      float hSW = bf2f(hS.u[j]), hSc = bf2f(hS.u[j + 1]), hSE = bf2f(hS.u[j + 2]);
      float uA = ngf * (hSW + hSc - hNc - hNW) / fdx;
      float uB = ngf * (hSc + hSE - hNE - hNc) / fdx;
      float vA = pgf * (hE + hNE - hNW - hW) / fdx;
      float vB = pgf * (hSE + hE - hW - hSW) / fdx;
      float uT = 0.5f * (uA + uB);
      float vT = 0.5f * (vA + vB);
      float up = fmaxf(uT, 0.f), um = fminf(uT, 0.f);
      float vp = fmaxf(vT, 0.f), vm = fminf(vT, 0.f);
      float qbc = bf2f(qC.u[j + 9]);
      float d0 = 0.f, dE = 0.f, dW = 0.f, dEE = 0.f, dWW = 0.f;
      float dSv = 0.f, dNv = 0.f, dSSv = 0.f, dNNv = 0.f;
      if (!FIRST) {
        d0 = bf2f(dC.u[j + 8]);  dE = bf2f(dC.u[j + 9]);  dW = bf2f(dC.u[j + 7]);
        dEE = bf2f(dC.u[j + 10]); dWW = bf2f(dC.u[j + 6]);
        dSv = bf2f(dS.u[j]);  dNv = bf2f(dN.u[j]);
        dSSv = bf2f(dSS.u[j]); dNNv = bf2f(dNN.u[j]);
      }
      float Q0  = qbc + d0;
      float QE  = bf2f(qC.u[j + 10]) + dE,  QW  = bf2f(qC.u[j + 8]) + dW;
      float QEE = bf2f(qC.u[j + 11]) + dEE, QWW = bf2f(qC.u[j + 7]) + dWW;
      float QS  = bf2f(qS.u[j + 1]) + dSv,  QN  = bf2f(qN.u[j + 1]) + dNv;
      float QSS = bf2f(qSS.u[j + 1]) + dSSv, QNN = bf2f(qNN.u[j + 1]) + dNNv;
      float r = -up * cc * (2.f * QE + 3.f * Q0 - 6.f * QW + QWW)
              + um * cc * (QEE - 6.f * QE + 3.f * Q0 + 2.f * QW)
              - vp * cc * (2.f * QS + 3.f * Q0 - 6.f * QN + QNN)
              + vm * cc * (QSS - 6.f * QS + 3.f * Q0 + 2.f * QN);
      float q1 = Q0 + dtf * r;
      q1 = fminf(fmaxf(q1, -QCLAMP), QCLAMP);
      val = q1 - qbc;
    }
    res.u[j] = f2bf(val);
  }
  *(short8*)OUT = res.s;
}

// ---------------- solve core: acc2 = S @ (S @ X^T)^T for one (s,q,w) ----------------
__device__ inline f32x16 solve_core(const unsigned short* __restrict__ Sm,
                                    const unsigned short* __restrict__ X,
                                    unsigned short* __restrict__ Ul,
                                    int q, int w, int r31, int kh) {
  f32x16 acc;
#pragma unroll
  for (int i = 0; i < 16; ++i) acc[i] = 0.f;
  {
    const int ar = (32 * q + r31) * 256;
    const int br = (32 * w + r31) * 256;
#pragma unroll 4
    for (int kc = 0; kc < 256; kc += 16) {
      short8 a = *(const short8*)&Sm[ar + kc + kh * 8];
      short8 b = *(const short8*)&X[br + kc + kh * 8];
      acc = __builtin_amdgcn_mfma_f32_32x32x16_bf16(a, b, acc, 0, 0, 0);
    }
  }
  {
    const int col = 32 * w + r31;
    const int g = col >> 3, c7 = col & 7;
#pragma unroll
    for (int reg = 0; reg < 16; ++reg) {
      int i = (reg & 3) + 8 * (reg >> 2) + 4 * kh;
      Ul[i * 256 + (((g ^ (i & 7)) << 3) | c7)] = f2bf(acc[reg]);
    }
  }
  __syncthreads();
  f32x16 acc2;
#pragma unroll
  for (int i = 0; i < 16; ++i) acc2[i] = 0.f;
  {
    const int ar = (32 * w + r31) * 256;
    const int urow = r31 * 256;
    const int x7 = (r31 & 7);
#pragma unroll 4
    for (int kc = 0; kc < 256; kc += 16) {
      int g0 = (kc >> 3) + kh;
      short8 a = *(const short8*)&Sm[ar + kc + kh * 8];
      short8 b = *(const short8*)&Ul[urow + ((g0 ^ x7) << 3)];
      acc2 = __builtin_amdgcn_mfma_f32_32x32x16_bf16(a, b, acc2, 0, 0, 0);
    }
  }
  return acc2;
}

// ---------------- fused half-solve: one dstI2D ----------------
template <int EPI>
__global__ __launch_bounds__(512) void k_solve(const unsigned short* __restrict__ Sm,
                                               const unsigned short* __restrict__ Xb,
                                               unsigned short* __restrict__ Ob,
                                               const float* __restrict__ HM,
                                               const float* __restrict__ xin,
                                               unsigned short* __restrict__ hout,
                                               double* __restrict__ part) {
  __shared__ unsigned short Ul[32 * 256];
  const int s = blockIdx.x, q = blockIdx.y;
  const int lane = threadIdx.x & 63, w = threadIdx.x >> 6;
  const int r31 = lane & 31, kh = lane >> 5;
  f32x16 acc2 = solve_core(Sm, Xb + (size_t)s * NPIX, Ul, q, w, r31, kh);
  const int gn = 32 * q + r31;
  if (EPI == 0) {
    unsigned short* O = Ob + (size_t)s * NPIX;
#pragma unroll
    for (int reg = 0; reg < 16; ++reg) {
      int gm = 32 * w + (reg & 3) + 8 * (reg >> 2) + 4 * kh;
      O[(size_t)gm * 256 + gn] = f2bf(acc2[reg] / HM[(size_t)gm * 256 + gn]);
    }
  } else if (EPI == 1) {
    int b = s / 14, t = s - b * 14;
    const float* hb = xin + (size_t)(b * 15 + t) * NPIX;
    unsigned short* H = hout + (size_t)s * NPIX;
    if (gn < 254) {
#pragma unroll
      for (int reg = 0; reg < 16; ++reg) {
        int gm = 32 * w + (reg & 3) + 8 * (reg >> 2) + 4 * kh;
        if (gm < 254) {
          size_t o = (size_t)(gm + 1) * 256 + (gn + 1);
          float hv = acc2[reg] + hb[o];
          H[o] = f2bf(fminf(fmaxf(hv, -HCLAMP), HCLAMP));
        }
      }
    }
  } else {
    int b = s / 14, t = s - b * 14;
    const float* hb = xin + (size_t)(b * 15 + t) * NPIX;
    const float* x1 = xin + (size_t)(b * 15 + t + 1) * NPIX;
    double dsum = 0.0;
    if (gn < 254) {
#pragma unroll
      for (int reg = 0; reg < 16; ++reg) {
        int gm = 32 * w + (reg & 3) + 8 * (reg >> 2) + 4 * kh;
        if (gm < 254) {
          size_t o = (size_t)(gm + 1) * 256 + (gn + 1);
          float hv = acc2[reg] + hb[o];
          hv = fminf(fmaxf(hv, -HCLAMP), HCLAMP);
          float d = x1[o] - hv;
          dsum += (double)d * (double)d;
        }
      }
    }
    for (int o = 32; o > 0; o >>= 1) dsum += __shfl_down(dsum, o);
    __shared__ double sred[8];
    if (lane == 0) sred[w] = dsum;
    __syncthreads();
    if (threadIdx.x == 0) {
      double t8 = 0.0;
#pragma unroll
      for (int i = 0; i < 8; ++i) t8 += sred[i];
      part[1024 + s * 8 + q] = t8;
    }
  }
}

// ---------------- conv64, 512 thr: 8 waves = 4 rowgroups x 2 oc-halves ----------------
template <bool RELU>
__global__ __launch_bounds__(512) void k_conv64b(const unsigned short* __restrict__ in,
                                                 const unsigned short* __restrict__ wt,
                                                 const float* __restrict__ bias,
                                                 unsigned short* __restrict__ out) {
  __shared__ unsigned short tile[324 * 64];
  const int tid = threadIdx.x;
  const int lane = tid & 63, wave = tid >> 6;
  const int cl = lane & 15, kg = lane >> 4;
  const int wrow = wave & 3, wh = wave >> 2;
  const int b = blockIdx.z;
  const int gx0 = blockIdx.x * 16, gy0 = blockIdx.y * 16;

  f32x4 acc[4][2];
#pragma unroll
  for (int j = 0; j < 2; ++j) {
    float bv = bias[wh * 32 + j * 16 + cl];
#pragma unroll
    for (int i = 0; i < 4; ++i) acc[i][j] = (f32x4){bv, bv, bv, bv};
  }

  const unsigned short* inb = in + (size_t)b * NPIX * 64;
  for (int c = tid; c < 2592; c += 512) {
    int pp = c >> 3, g = c & 7;
    int ly = pp / 18, lx = pp - ly * 18;
    int iy = gy0 + ly - 1, ix = gx0 + lx - 1;
    uint4 v = make_uint4(0u, 0u, 0u, 0u);
    if (iy >= 0 && iy < 256 && ix >= 0 && ix < 256)
      v = *(const uint4*)&inb[((size_t)iy * 256 + ix) * 64 + g * 8];
    int sw = g ^ (pp & 7);
    *(uint4*)&tile[pp * 64 + sw * 8] = v;
  }
  __syncthreads();

#pragma unroll 3
  for (int cm = 0; cm < 18; ++cm) {
    const int tap = cm >> 1;
    const int g = (cm & 1) * 4 + kg;
    const int dy = tap / 3, dxx = tap - dy * 3;
    short8 bfr[2];
#pragma unroll
    for (int j = 0; j < 2; ++j)
      bfr[j] = *(const short8*)&wt[(((size_t)cm * 4 + kg) * 64 + wh * 32 + j * 16 + cl) * 8];
    const int tc = cl + dxx;
#pragma unroll
    for (int i = 0; i < 4; ++i) {
      int pp = (wrow * 4 + i + dy) * 18 + tc;
      int g2 = g ^ (pp & 7);
      short8 av = *(const short8*)&tile[pp * 64 + g2 * 8];
#pragma unroll
      for (int j = 0; j < 2; ++j)
        acc[i][j] = __builtin_amdgcn_mfma_f32_16x16x32_bf16(av, bfr[j], acc[i][j], 0, 0, 0);
    }
  }

  const size_t outBase = (size_t)b * NPIX * 64;
#pragma unroll
  for (int i = 0; i < 4; ++i) {
    int y = gy0 + wrow * 4 + i;
#pragma unroll
    for (int j = 0; j < 2; ++j) {
      int oc = wh * 32 + j * 16 + cl;
#pragma unroll
      for (int r = 0; r < 4; ++r) {
        int px = gx0 + kg * 4 + r;
        size_t oi = outBase + ((size_t)y * 256 + px) * 64 + oc;
        float v = acc[i][j][r];
        if (RELU) v = fmaxf(v, 0.f);
        out[oi] = f2bf(v);
      }
    }
  }
}

// ---------------- k_conv3: stage z2 once; b1 -> z1out, then b21*b22 -> bc ----------
__global__ __launch_bounds__(512) void k_conv3(const unsigned short* __restrict__ in,
                                               const unsigned short* __restrict__ wt1,
                                               const unsigned short* __restrict__ wtA,
                                               const unsigned short* __restrict__ wtB,
                                               const float* __restrict__ bias1,
                                               const float* __restrict__ biasA,
                                               const float* __restrict__ biasB,
                                               unsigned short* __restrict__ out1,
                                               unsigned short* __restrict__ outm) {
  __shared__ unsigned short tile[324 * 64];
  const int tid = threadIdx.x;
  const int lane = tid & 63, wave = tid >> 6;
  const int cl = lane & 15, kg = lane >> 4;
  const int wrow = wave & 3, wh = wave >> 2;
  const int b = blockIdx.z;
  const int gx0 = blockIdx.x * 16, gy0 = blockIdx.y * 16;
  const size_t outBase = (size_t)b * NPIX * 64;

  const unsigned short* inb = in + (size_t)b * NPIX * 64;
  for (int c = tid; c < 2592; c += 512) {
    int pp = c >> 3, g = c & 7;
    int ly = pp / 18, lx = pp - ly * 18;
    int iy = gy0 + ly - 1, ix = gx0 + lx - 1;
    uint4 v = make_uint4(0u, 0u, 0u, 0u);
    if (iy >= 0 && iy < 256 && ix >= 0 && ix < 256)
      v = *(const uint4*)&inb[((size_t)iy * 256 + ix) * 64 + g * 8];
    int sw = g ^ (pp & 7);
    *(uint4*)&tile[pp * 64 + sw * 8] = v;
  }
  __syncthreads();

  // ---- phase 1: b1 conv ----
  {
    f32x4 acc[4][2];
#pragma unroll
    for (int j = 0; j < 2; ++j) {
      float bv = bias1[wh * 32 + j * 16 + cl];
#pragma unroll
      for (int i = 0; i < 4; ++i) acc[i][j] = (f32x4){bv, bv, bv, bv};
    }
#pragma unroll 3
    for (int cm = 0; cm < 18; ++cm) {
      const int tap = cm >> 1;
      const int g = (cm & 1) * 4 + kg;
      const int dy = tap / 3, dxx = tap - dy * 3;
      short8 bfr[2];
#pragma unroll
      for (int j = 0; j < 2; ++j)
        bfr[j] = *(const short8*)&wt1[(((size_t)cm * 4 + kg) * 64 + wh * 32 + j * 16 + cl) * 8];
      const int tc = cl + dxx;
#pragma unroll
      for (int i = 0; i < 4; ++i) {
        int pp = (wrow * 4 + i + dy) * 18 + tc;
        int g2 = g ^ (pp & 7);
        short8 av = *(const short8*)&tile[pp * 64 + g2 * 8];
#pragma unroll
        for (int j = 0; j < 2; ++j)
          acc[i][j] = __builtin_amdgcn_mfma_f32_16x16x32_bf16(av, bfr[j], acc[i][j], 0, 0, 0);
      }
    }
#pragma unroll
    for (int i = 0; i < 4; ++i) {
      int y = gy0 + wrow * 4 + i;
#pragma unroll
      for (int j = 0; j < 2; ++j) {
        int oc = wh * 32 + j * 16 + cl;
#pragma unroll
        for (int r = 0; r < 4; ++r) {
          int px = gx0 + kg * 4 + r;
          out1[outBase + ((size_t)y * 256 + px) * 64 + oc] = f2bf(acc[i][j][r]);
        }
      }
    }
  }

  // ---- phase 2: b21 and b22 convs, write product ----
  {
    f32x4 accA[4][2], accB[4][2];
#pragma unroll
    for (int j = 0; j < 2; ++j) {
      float ba = biasA[wh * 32 + j * 16 + cl], bb = biasB[wh * 32 + j * 16 + cl];
#pragma unroll
      for (int i = 0; i < 4; ++i) {
        accA[i][j] = (f32x4){ba, ba, ba, ba};
        accB[i][j] = (f32x4){bb, bb, bb, bb};
      }
    }
#pragma unroll 2
    for (int cm = 0; cm < 18; ++cm) {
      const int tap = cm >> 1;
      const int g = (cm & 1) * 4 + kg;
      const int dy = tap / 3, dxx = tap - dy * 3;
      const int tc = cl + dxx;
      short8 wa[2], wb[2];
#pragma unroll
      for (int j = 0; j < 2; ++j) {
        wa[j] = *(const short8*)&wtA[(((size_t)cm * 4 + kg) * 64 + wh * 32 + j * 16 + cl) * 8];
        wb[j] = *(const short8*)&wtB[(((size_t)cm * 4 + kg) * 64 + wh * 32 + j * 16 + cl) * 8];
      }
#pragma unroll
      for (int i = 0; i < 4; ++i) {
        int pp = (wrow * 4 + i + dy) * 18 + tc;
        int g2 = g ^ (pp & 7);
        short8 av = *(const short8*)&tile[pp * 64 + g2 * 8];
#pragma unroll
        for (int j = 0; j < 2; ++j) {
          accA[i][j] = __builtin_amdgcn_mfma_f32_16x16x32_bf16(av, wa[j], accA[i][j], 0, 0, 0);
          accB[i][j] = __builtin_amdgcn_mfma_f32_16x16x32_bf16(av, wb[j], accB[i][j], 0, 0, 0);
        }
      }
    }
#pragma unroll
    for (int i = 0; i < 4; ++i) {
      int y = gy0 + wrow * 4 + i;
#pragma unroll
      for (int j = 0; j < 2; ++j) {
        int oc = wh * 32 + j * 16 + cl;
#pragma unroll
        for (int r = 0; r < 4; ++r) {
          int px = gx0 + kg * 4 + r;
          outm[outBase + ((size_t)y * 256 + px) * 64 + oc] = f2bf(accA[i][j][r] * accB[i][j][r]);
        }
      }
    }
  }
}

// ---------------- out conv: dual source, 16 oc, 512 thr (2 rows/wave) -------------
__global__ __launch_bounds__(512) void k_convout(const unsigned short* __restrict__ in0,
                                                 const unsigned short* __restrict__ in1,
                                                 const unsigned short* __restrict__ wt,
                                                 const float* __restrict__ bias,
                                                 unsigned short* __restrict__ out) {
  __shared__ unsigned short tile[324 * 64];
  const int tid = threadIdx.x;
  const int lane = tid & 63, wave = tid >> 6;
  const int cl = lane & 15, kg = lane >> 4;
  const int b = blockIdx.z;
  const int gx0 = blockIdx.x * 16, gy0 = blockIdx.y * 16;

  f32x4 acc[2];
  {
    float bv = (cl < 15) ? bias[cl] : 0.f;
    acc[0] = (f32x4){bv, bv, bv, bv};
    acc[1] = acc[0];
  }

  for (int src = 0; src < 2; ++src) {
    const unsigned short* inb = (src ? in1 : in0) + (size_t)b * NPIX * 64;
    const unsigned short* wtp = wt + src * 9216;
    if (src) __syncthreads();
    for (int c = tid; c < 2592; c += 512) {
      int pp = c >> 3, g = c & 7;
      int ly = pp / 18, lx = pp - ly * 18;
      int iy = gy0 + ly - 1, ix = gx0 + lx - 1;
      uint4 v = make_uint4(0u, 0u, 0u, 0u);
      if (iy >= 0 && iy < 256 && ix >= 0 && ix < 256)
        v = *(const uint4*)&inb[((size_t)iy * 256 + ix) * 64 + g * 8];
      int sw = g ^ (pp & 7);
      *(uint4*)&tile[pp * 64 + sw * 8] = v;
    }
    __syncthreads();
#pragma unroll 3
    for (int cm = 0; cm < 18; ++cm) {
      const int tap = cm >> 1;
      const int g = (cm & 1) * 4 + kg;
      const int dy = tap / 3, dxx = tap - dy * 3;
      short8 bfr = *(const short8*)&wtp[(((size_t)cm * 4 + kg) * 16 + cl) * 8];
      const int tc = cl + dxx;
#pragma unroll
      for (int i = 0; i < 2; ++i) {
        int pp = (wave * 2 + i + dy) * 18 + tc;
        int g2 = g ^ (pp & 7);
        short8 av = *(const short8*)&tile[pp * 64 + g2 * 8];
        acc[i] = __builtin_amdgcn_mfma_f32_16x16x32_bf16(av, bfr, acc[i], 0, 0, 0);
      }
    }
  }

  const size_t outBase = (size_t)b * NPIX * 16;
#pragma unroll
  for (int i = 0; i < 2; ++i) {
    int y = gy0 + wave * 2 + i;
#pragma unroll
    for (int r = 0; r < 4; ++r) {
      int px = gx0 + kg * 4 + r;
      size_t oi = outBase + ((size_t)y * 256 + px) * 16 + cl;
      out[oi] = f2bf(acc[i][r]);
    }
  }
}

// ---------------- conv16 (conv_in), 256 thr ----------------
__global__ __launch_bounds__(256) void k_conv16(const unsigned short* __restrict__ in,
                                                const unsigned short* __restrict__ wt,
                                                const float* __restrict__ bias,
                                                unsigned short* __restrict__ out) {
  __shared__ unsigned short wlds[10240];
  __shared__ unsigned short tile[324 * 16];

  const int tid = threadIdx.x;
  const int lane = tid & 63, wave = tid >> 6;
  const int cl = lane & 15, kg = lane >> 4;
  const int b = blockIdx.z;
  const int gx0 = blockIdx.x * 16, gy0 = blockIdx.y * 16;

  {
    uint4* wl = (uint4*)wlds;
    const uint4* wg = (const uint4*)wt;
    for (int i = tid; i < 1280; i += 256) wl[i] = wg[i];
  }
  const unsigned short* inb = in + (size_t)b * NPIX * 16;
  for (int c = tid; c < 648; c += 256) {
    int pp = c >> 1, g = c & 1;
    int ly = pp / 18, lx = pp - ly * 18;
    int iy = gy0 + ly - 1, ix = gx0 + lx - 1;
    uint4 v = make_uint4(0u, 0u, 0u, 0u);
    if (iy >= 0 && iy < 256 && ix >= 0 && ix < 256)
      v = *(const uint4*)&inb[((size_t)iy * 256 + ix) * 16 + g * 8];
    int sw = g ^ (pp & 1);
    *(uint4*)&tile[pp * 16 + sw * 8] = v;
  }
  __syncthreads();

  f32x4 acc[4][4];
#pragma unroll
  for (int j = 0; j < 4; ++j) {
    float bv = bias[j * 16 + cl];
#pragma unroll
    for (int i = 0; i < 4; ++i) acc[i][j] = (f32x4){bv, bv, bv, bv};
  }

#pragma unroll
  for (int c = 0; c < 5; ++c) {
    int tap = 2 * c + (kg >> 1);
    int dy = tap / 3, dxx = tap - dy * 3;
    int gidx = kg & 1;
    short8 bfr[4];
#pragma unroll
    for (int j = 0; j < 4; ++j)
      bfr[j] = *(const short8*)&wlds[((c * 4 + kg) * 64 + j * 16 + cl) * 8];
    int tc = cl + dxx;
#pragma unroll
    for (int i = 0; i < 4; ++i) {
      int tr = wave * 4 + i + dy;
      if (tr > 17) tr = 17;
      int pp = tr * 18 + tc;
      int g2 = gidx ^ (pp & 1);
      short8 av = *(const short8*)&tile[pp * 16 + g2 * 8];
#pragma unroll
      for (int j = 0; j < 4; ++j)
        acc[i][j] = __builtin_amdgcn_mfma_f32_16x16x32_bf16(av, bfr[j], acc[i][j], 0, 0, 0);
    }
  }

  const size_t outBase = (size_t)b * NPIX * 64;
#pragma unroll
  for (int i = 0; i < 4; ++i) {
    int y = gy0 + wave * 4 + i;
#pragma unroll
    for (int j = 0; j < 4; ++j) {
      int oc = j * 16 + cl;
#pragma unroll
      for (int r = 0; r < 4; ++r) {
        int px = gx0 + kg * 4 + r;
        size_t oi = outBase + ((size_t)y * 256 + px) * 64 + oc;
        out[oi] = f2bf(fmaxf(acc[i][j][r], 0.f));
      }
    }
  }
}

// ---------------- ae reduction (coalesced) + ticket final ----------------
__global__ __launch_bounds__(256) void k_red_ae(const float* __restrict__ x,
                                                const unsigned short* __restrict__ xa,
                                                double* __restrict__ part,
                                                unsigned int* __restrict__ cnt,
                                                float* __restrict__ out) {
  const int NBT = 1024;
  const int bid = blockIdx.x;
  const int tid = threadIdx.x;
  const int e = bid * 256 + tid;
  const int b = e >> 16, p = e & 65535;
  union { unsigned short u16[16]; uint4 u4[2]; } vv;
  const uint4* xap = (const uint4*)&xa[(size_t)e * 16];
  vv.u4[0] = xap[0];
  vv.u4[1] = xap[1];
  const float* xb = x + (size_t)b * 15 * NPIX + p;
  double sum = 0.0;
#pragma unroll
  for (int c = 0; c < 15; ++c) {
    float d = xb[(size_t)c * NPIX] - bf2f(vv.u16[c]);
    sum += (double)d * (double)d;
  }
  for (int o = 32; o > 0; o >>= 1) sum += __shfl_down(sum, o);
  __shared__ double sw[4];
  __shared__ bool last;
  int lane = tid & 63, wid = tid >> 6;
  if (lane == 0) sw[wid] = sum;
  __syncthreads();
  if (tid == 0) {
    part[bid] = sw[0] + sw[1] + sw[2] + sw[3];
    __threadfence();
    unsigned int t = atomicAdd(cnt, 1u);
    last = (t == (unsigned)(NBT - 1));
  }
  __syncthreads();
  if (last) {
    __threadfence();
    double s1 = 0.0, s2 = 0.0;
    for (int i = tid; i < 504; i += 256) s1 += part[1024 + i];
    for (int i = tid; i < NBT; i += 256) s2 += part[i];
    for (int o = 32; o > 0; o >>= 1) {
      s1 += __shfl_down(s1, o);
      s2 += __shfl_down(s2, o);
    }
    __shared__ double a1[4], a2[4];
    if (lane == 0) { a1[wid] = s1; a2[wid] = s2; }
    __syncthreads();
    if (tid == 0) {
      double v = (a1[0] + a1[1] + a1[2] + a1[3]) / (double)(NS * NPIX)
               + (a2[0] + a2[1] + a2[2] + a2[3]) / (double)(60 * NPIX);
      if (!(v == v)) v = 0.0;
      if (v > 1.0e30) v = 1.0e30;
      if (v < -1.0e30) v = -1.0e30;
      out[0] = (float)v;
    }
  }
}

// ---------------- launcher ----------------
extern "C" void kernel_launch(void* const* d_in, const int* in_sizes, int n_in,
                              void* d_out, int out_size, void* d_ws, size_t ws_size,
                              hipStream_t stream) {
  (void)in_sizes; (void)n_in; (void)out_size; (void)ws_size;
  const float* x     = (const float*)d_in[0];
  const float* w_in  = (const float*)d_in[1];
  const float* b_in  = (const float*)d_in[2];
  const float* w_hid = (const float*)d_in[3];
  const float* b_hid = (const float*)d_in[4];
  const float* w_b1  = (const float*)d_in[5];
  const float* b_b1  = (const float*)d_in[6];
  const float* w_b21 = (const float*)d_in[7];
  const float* b_b21 = (const float*)d_in[8];
  const float* w_b22 = (const float*)d_in[9];
  const float* b_b22 = (const float*)d_in[10];
  const float* w_out = (const float*)d_in[11];
  const float* b_out = (const float*)d_in[12];
  float* ws = (float*)d_ws;
  float* out = (float*)d_out;

  double mc = 0.0;
  for (int k = 0; k < 256; ++k) mc += cos((32.0 + 0.05 * k) * D_PI / 180.0);
  mc /= 256.0;
  float DXf = (float)(0.5 * (5550.0 + 5550.0 * mc));
  float dx2 = DXf * DXf;
  float gf  = (float)(9.81 / 1e-4);
  float ngf = (float)(-9.81 / 1e-4);
  float gfc = (float)(9.81 * 1e-4 / (2.7 * 2.7));
  float fdx = 4.0f * DXf;
  float cc  = 1.0f / (6.0f * DXf);
  float dtf = 21600.0f;

  double* part = (double*)d_ws;
  unsigned int* cnt = (unsigned int*)(ws + OFF_CNT);
  unsigned short* S  = (unsigned short*)(ws + OFF_S);
  float* HM = ws + OFF_HM;
  unsigned short* h  = (unsigned short*)(ws + OFF_H);
  unsigned short* qb = (unsigned short*)(ws + OFF_QB);
  unsigned short* dq0 = (unsigned short*)(ws + OFF_DQ0);
  unsigned short* dq1 = (unsigned short*)(ws + OFF_DQ1);
  unsigned short* A1 = (unsigned short*)(ws + OFF_A1);
  unsigned short* xp = (unsigned short*)(ws + OFF_XP);
  unsigned short* z1 = (unsigned short*)(ws + OFF_Z1);
  unsigned short* z2 = (unsigned short*)(ws + OFF_Z2);
  unsigned short* bc = (unsigned short*)(ws + OFF_BC);
  unsigned short* xa = (unsigned short*)(ws + OFF_XA);
  unsigned short* wtb = (unsigned short*)(ws + OFF_WT);

  k_preamble<<<dim3(16680), dim3(256), 0, stream>>>(x, w_in, w_hid, w_b1, w_b21, w_b22,
                                                    w_out, S, HM, wtb, h, qb, xp, cnt,
                                                    part, dx2, gf, gfc);

  dim3 sg(56, 8);
  dim3 qg8(NS * 8192 / 256);   // 1792 blocks, 8 px per thread
  unsigned short* dqc = dq0;
  unsigned short* dqn = dq1;
  for (int step = 0; step < 4; ++step) {
    if (step == 0)
      k_qrhs_v8<true><<<qg8, dim3(256), 0, stream>>>(h, qb, dq1, dqc, ngf, gf, fdx, cc, dtf);
    else {
      k_qrhs_v8<false><<<qg8, dim3(256), 0, stream>>>(h, qb, dqc, dqn, ngf, gf, fdx, cc, dtf);
      unsigned short* tmp = dqc; dqc = dqn; dqn = tmp;
    }
    k_solve<0><<<sg, dim3(512), 0, stream>>>(S, dqc, A1, HM, nullptr, nullptr, part);
    if (step < 3)
      k_solve<1><<<sg, dim3(512), 0, stream>>>(S, A1, nullptr, nullptr, x, h, part);
    else
      k_solve<2><<<sg, dim3(512), 0, stream>>>(S, A1, nullptr, nullptr, x, nullptr, part);
  }

  dim3 cg4(16, 16, 4);
  k_conv16<<<cg4, dim3(256), 0, stream>>>(xp, wtb + W_IN, b_in, z1);
  k_conv64b<false><<<cg4, dim3(512), 0, stream>>>(z1, wtb + W_HID, b_hid, z2);
  k_conv3<<<cg4, dim3(512), 0, stream>>>(z2, wtb + W_B1, wtb + W_B21, wtb + W_B22,
                                         b_b1, b_b21, b_b22, z1, bc);
  k_convout<<<cg4, dim3(512), 0, stream>>>(z1, bc, wtb + W_O1, b_out, xa);

  k_red_ae<<<dim3(1024), dim3(256), 0, stream>>>(x, xa, part, cnt, out);
}